// Round 7
// baseline (219.063 us; speedup 1.0000x reference)
//
#include <hip/hip_runtime.h>
#include <math.h>

#define SB   2
#define SEQ  2048
#define FDIM 1024
#define NH   16
#define HD   64
#define BH   (SB * NH)   // 32
#define LK   72          // attention LDS row stride in f16 elems (64 + 8 pad)

typedef _Float16 half8 __attribute__((ext_vector_type(8)));
typedef __attribute__((ext_vector_type(4))) float floatx4;
typedef __attribute__((ext_vector_type(16))) float floatx16;
typedef unsigned int uintx4 __attribute__((ext_vector_type(4)));
typedef unsigned int uint2v __attribute__((ext_vector_type(2)));

__device__ __forceinline__ unsigned pk_f16(float a, float b) {
    unsigned short ha = __builtin_bit_cast(unsigned short, (_Float16)a);
    unsigned short hb = __builtin_bit_cast(unsigned short, (_Float16)b);
    return (unsigned)ha | ((unsigned)hb << 16);
}
__device__ __forceinline__ unsigned short f16_1(float a) {
    _Float16 h = (_Float16)a;
    return __builtin_bit_cast(unsigned short, h);
}
__device__ __forceinline__ void load16_lds(const unsigned short* g, unsigned short* l) {
    __builtin_amdgcn_global_load_lds(
        (const __attribute__((address_space(1))) unsigned int*)g,
        (__attribute__((address_space(3))) unsigned int*)l, 16, 0, 0);
}
// hazard-safe permlane32_swap via builtin: swaps a.hi32lanes <-> b.lo32lanes
__device__ __forceinline__ void pl32(unsigned &a, unsigned &b) {
    uint2v r = __builtin_amdgcn_permlane32_swap(a, b, false, false);
    a = r[0]; b = r[1];
}
__device__ __forceinline__ half8 bc4(unsigned a, unsigned b, unsigned c, unsigned d) {
    uintx4 t; t[0] = a; t[1] = b; t[2] = c; t[3] = d;
    return __builtin_bit_cast(half8, t);
}
__device__ __forceinline__ floatx16 zero16() {
    floatx16 z;
    #pragma unroll
    for (int i = 0; i < 16; ++i) z[i] = 0.f;
    return z;
}

// ---------------------------------------------------------------------------
// fp32 -> f16: both activations in one launch. blockIdx.x < 2048 -> from.
// ---------------------------------------------------------------------------
__global__ __launch_bounds__(256) void cvt_act(
    const float* __restrict__ in0, const float* __restrict__ in1,
    unsigned short* __restrict__ out0, unsigned short* __restrict__ out1)
{
    int bx = blockIdx.x;
    const float* in = (bx < 2048) ? in0 : in1;
    unsigned short* out = (bx < 2048) ? out0 : out1;
    int i = ((bx & 2047) * 256 + threadIdx.x) * 8;
    float4 a = *(const float4*)(in + i);
    float4 b = *(const float4*)(in + i + 4);
    uint4 o;
    o.x = pk_f16(a.x, a.y); o.y = pk_f16(a.z, a.w);
    o.z = pk_f16(b.x, b.y); o.w = pk_f16(b.z, b.w);
    *(uint4*)(out + i) = o;
}

// ---------------------------------------------------------------------------
// All three W [K][N] fp32 -> Wt [N][K] f16 in one launch (64x64 LDS tiles).
// ---------------------------------------------------------------------------
__global__ __launch_bounds__(256) void cvt_w(
    const float* __restrict__ Wq, const float* __restrict__ Wkv,
    const float* __restrict__ Wo, unsigned short* __restrict__ Wqt,
    unsigned short* __restrict__ Wkvt, unsigned short* __restrict__ Wot)
{
    __shared__ float T[64 * 65];
    const int tid = threadIdx.x;
    int id = blockIdx.x;
    const float* W; unsigned short* Wt; int N, n0, k0;
    if (id < 256)      { W = Wq;  Wt = Wqt;  N = 1024; n0 = (id & 15) << 6; k0 = (id >> 4) << 6; }
    else if (id < 768) { id -= 256; W = Wkv; Wt = Wkvt; N = 2048; n0 = (id & 31) << 6; k0 = (id >> 5) << 6; }
    else               { id -= 768; W = Wo;  Wt = Wot;  N = 1024; n0 = (id & 15) << 6; k0 = (id >> 4) << 6; }

    #pragma unroll
    for (int i = 0; i < 4; ++i) {
        int idx = tid + (i << 8);
        int row = idx >> 4, c4 = idx & 15;
        float4 v = *(const float4*)(W + (size_t)(k0 + row) * N + n0 + (c4 << 2));
        float* tp = &T[row * 65 + (c4 << 2)];
        tp[0] = v.x; tp[1] = v.y; tp[2] = v.z; tp[3] = v.w;
    }
    __syncthreads();
    #pragma unroll
    for (int i = 0; i < 4; ++i) {
        int idx = tid + (i << 8);
        int n = idx >> 4, c4 = idx & 15;
        float x = T[(c4 * 4 + 0) * 65 + n];
        float y = T[(c4 * 4 + 1) * 65 + n];
        float z = T[(c4 * 4 + 2) * 65 + n];
        float w = T[(c4 * 4 + 3) * 65 + n];
        uint2 o = make_uint2(pk_f16(x, y), pk_f16(z, w));
        *(uint2*)(Wt + (size_t)(n0 + n) * FDIM + k0 + (c4 << 2)) = o;
    }
}

// ---------------------------------------------------------------------------
// f16 MFMA GEMM core: acc = A @ Wt^T, 128x128 tile, BK=64 (halves barrier
// drains vs BK=32). LDS tiles [128][64] f16 stay LINEAR for global_load_lds;
// bank conflicts (row stride 128B = all 32 banks) are avoided with the
// both-sides chunk-XOR swizzle (rule: swizzle source AND read, or neither):
// staging fetches global 16B-chunk j^(row&7) into linear LDS slot j; the
// fragment read XORs the same involution -> 2 lanes/bank (free).
// ---------------------------------------------------------------------------
__device__ __forceinline__ void gemm_core(
    const unsigned short* __restrict__ A, const unsigned short* __restrict__ Wt,
    int m0, int n0, int K, floatx4 (&acc)[4][4],
    unsigned short* Al, unsigned short* Bl)
{
    const int tid  = threadIdx.x;
    const int w    = tid >> 6;
    const int lane = tid & 63;
    const int q    = lane >> 4, l = lane & 15;
    const int wm = (w >> 1) * 64, wn = (w & 1) * 64;

    for (int k0 = 0; k0 < K; k0 += 64) {
        __syncthreads();
        #pragma unroll
        for (int it = 0; it < 4; ++it) {
            int c = (w * 4 + it) * 64 + lane;      // chunk id 0..1023
            int row = c >> 3;
            int jsrc = (c & 7) ^ (row & 7);        // source-side swizzle
            load16_lds(A  + (size_t)(m0 + row) * K + k0 + jsrc * 8, Al + c * 8);
            load16_lds(Wt + (size_t)(n0 + row) * K + k0 + jsrc * 8, Bl + c * 8);
        }
        __syncthreads();

        #pragma unroll
        for (int kk2 = 0; kk2 < 2; ++kk2) {
            half8 aF[4], bF[4];
            #pragma unroll
            for (int i = 0; i < 4; ++i) {
                int row = wm + 16 * i + l;
                int jc  = (q + 4 * kk2) ^ (row & 7);   // read-side swizzle
                aF[i] = *(const half8*)(Al + row * 64 + jc * 8);
            }
            #pragma unroll
            for (int jn = 0; jn < 4; ++jn) {
                int row = wn + 16 * jn + l;
                int jc  = (q + 4 * kk2) ^ (row & 7);
                bF[jn] = *(const half8*)(Bl + row * 64 + jc * 8);
            }
            #pragma unroll
            for (int i = 0; i < 4; ++i)
                #pragma unroll
                for (int jn = 0; jn < 4; ++jn)
                    acc[i][jn] = __builtin_amdgcn_mfma_f32_16x16x32_f16(
                        aF[i], bF[jn], acc[i][jn], 0, 0, 0);
        }
    }
}

// ---------------------------------------------------------------------------
// Merged Q + KV projection GEMM. grid (24, 32): bx<8 -> Q, else KV.
// Outputs f16 head layout [(b*NH+h)*SEQ + s]*HD + dd.
// ---------------------------------------------------------------------------
__global__ __launch_bounds__(256) void gemm_qkv(
    const unsigned short* __restrict__ Af, const unsigned short* __restrict__ At,
    const unsigned short* __restrict__ Wqt, const unsigned short* __restrict__ Wkvt,
    const float* __restrict__ bq, const float* __restrict__ bkv,
    unsigned short* __restrict__ Qo, unsigned short* __restrict__ Ko,
    unsigned short* __restrict__ Vo)
{
    __shared__ unsigned short Al[128 * 64];
    __shared__ unsigned short Bl[128 * 64];

    const int tid  = threadIdx.x;
    const int w    = tid >> 6;
    const int lane = tid & 63;
    const int q    = lane >> 4, l = lane & 15;
    const int wm = (w >> 1) * 64, wn = (w & 1) * 64;
    const int m0 = blockIdx.y * 128;

    bool isQ = blockIdx.x < 8;
    const unsigned short* A  = isQ ? Af : At;
    const unsigned short* Wt = isQ ? Wqt : Wkvt;
    const float* bias        = isQ ? bq : bkv;
    const int n0 = (isQ ? blockIdx.x : (blockIdx.x - 8)) * 128;

    floatx4 acc[4][4];
    #pragma unroll
    for (int i = 0; i < 4; ++i)
        #pragma unroll
        for (int j = 0; j < 4; ++j)
            acc[i][j] = (floatx4){0.f, 0.f, 0.f, 0.f};

    gemm_core(A, Wt, m0, n0, FDIM, acc, Al, Bl);

    float bj[4];
    #pragma unroll
    for (int j = 0; j < 4; ++j) bj[j] = bias[n0 + wn + 16 * j + l];

    #pragma unroll
    for (int i = 0; i < 4; ++i)
        #pragma unroll
        for (int j = 0; j < 4; ++j) {
            int n = n0 + wn + 16 * j + l;
            #pragma unroll
            for (int r = 0; r < 4; ++r) {
                int m = m0 + wm + 16 * i + 4 * q + r;
                float v = acc[i][j][r] + bj[j];
                int b = m >> 11, s = m & (SEQ - 1);
                if (isQ) {
                    int h = n >> 6, dd = n & 63;
                    Qo[((size_t)(b * NH + h) * SEQ + s) * HD + dd] = f16_1(v);
                } else {
                    int np = (n < FDIM) ? n : (n - FDIM);
                    unsigned short* Cd = (n < FDIM) ? Ko : Vo;
                    int h = np >> 6, dd = np & 63;
                    Cd[((size_t)(b * NH + h) * SEQ + s) * HD + dd] = f16_1(v);
                }
            }
        }
}

// ---------------------------------------------------------------------------
// Out-projection GEMM: fp32 output [M][N].
// ---------------------------------------------------------------------------
__global__ __launch_bounds__(256) void gemm_out(
    const unsigned short* __restrict__ A, const unsigned short* __restrict__ Wt,
    const float* __restrict__ bias, float* __restrict__ C)
{
    __shared__ unsigned short Al[128 * 64];
    __shared__ unsigned short Bl[128 * 64];

    const int tid  = threadIdx.x;
    const int w    = tid >> 6;
    const int lane = tid & 63;
    const int q    = lane >> 4, l = lane & 15;
    const int wm = (w >> 1) * 64, wn = (w & 1) * 64;
    const int m0 = blockIdx.y * 128, n0 = blockIdx.x * 128;

    floatx4 acc[4][4];
    #pragma unroll
    for (int i = 0; i < 4; ++i)
        #pragma unroll
        for (int j = 0; j < 4; ++j)
            acc[i][j] = (floatx4){0.f, 0.f, 0.f, 0.f};

    gemm_core(A, Wt, m0, n0, FDIM, acc, Al, Bl);

    float bj[4];
    #pragma unroll
    for (int j = 0; j < 4; ++j) bj[j] = bias[n0 + wn + 16 * j + l];

    #pragma unroll
    for (int i = 0; i < 4; ++i)
        #pragma unroll
        for (int j = 0; j < 4; ++j) {
            int n = n0 + wn + 16 * j + l;
            #pragma unroll
            for (int r = 0; r < 4; ++r) {
                int m = m0 + wm + 16 * i + 4 * q + r;
                C[(size_t)m * FDIM + n] = acc[i][j][r] + bj[j];
            }
        }
}

// ---------------------------------------------------------------------------
// V [bh][z][d] f16 -> Vt [bh][d][z] f16
// ---------------------------------------------------------------------------
__global__ __launch_bounds__(256) void transpose_v(
    const unsigned short* __restrict__ V, unsigned short* __restrict__ Vt)
{
    __shared__ unsigned short T[64 * 72];
    const int tid = threadIdx.x;
    const int zt = blockIdx.x & 31, bh = blockIdx.x >> 5;
    const int z0 = zt << 6;
    #pragma unroll
    for (int it = 0; it < 2; ++it) {
        int idx = tid + (it << 8);
        int row = idx >> 3, c8 = idx & 7;
        *(half8*)(&T[row * 72 + c8 * 8]) =
            *(const half8*)(V + ((size_t)bh * SEQ + z0 + row) * HD + c8 * 8);
    }
    __syncthreads();
    #pragma unroll
    for (int it = 0; it < 4; ++it) {
        int idx = tid + (it << 8);
        int d = idx >> 4, c4 = idx & 15;
        unsigned short a = T[(c4 * 4 + 0) * 72 + d];
        unsigned short b = T[(c4 * 4 + 1) * 72 + d];
        unsigned short c = T[(c4 * 4 + 2) * 72 + d];
        unsigned short e = T[(c4 * 4 + 3) * 72 + d];
        uint2 o = make_uint2((unsigned)a | ((unsigned)b << 16),
                             (unsigned)c | ((unsigned)e << 16));
        *(uint2*)(Vt + ((size_t)bh * HD + d) * SEQ + z0 + (c4 << 2)) = o;
    }
}

// ---------------------------------------------------------------------------
// Row s=0 of each (b,h): reference's fully-masked row -> uniform softmax over
// all 2048 columns -> O[b,0,h*64+d] = mean_z V[bh][z][d]. Writes Og row 0
// (merge_kernel skips s==0).
// ---------------------------------------------------------------------------
__global__ __launch_bounds__(256) void row0_kernel(
    const unsigned short* __restrict__ Vtg, unsigned short* __restrict__ Og)
{
    __shared__ float red[256];
    const int bh = blockIdx.x;
    const int tid = threadIdx.x;
    const int d = tid >> 2, part = tid & 3;
    const unsigned short* vp = Vtg + ((size_t)bh * HD + d) * SEQ + part * 512;
    float s = 0.f;
    #pragma unroll
    for (int i = 0; i < 64; ++i) {
        half8 v = *(const half8*)(vp + i * 8);
        #pragma unroll
        for (int j = 0; j < 8; ++j) s += (float)v[j];
    }
    red[tid] = s;
    __syncthreads();
    if (part == 0) {
        float t = red[tid] + red[tid + 1] + red[tid + 2] + red[tid + 3];
        const int b = bh >> 4, h = bh & 15;
        Og[(size_t)b * SEQ * FDIM + h * HD + d] = f16_1(t * (1.0f / 2048.0f));
    }
}

// ---------------------------------------------------------------------------
// Flash attention, swapped-operand 32x32x16 MFMA, in-register softmax (T12),
// z-SPLIT for occupancy (1024 blocks = 4 blocks/CU). Partial O + (m,l);
// merge_kernel combines.
// Block mapping: XCD affinity (same-bh blocks share bid%8) + CU balance
// (co-resident quads stage exactly 34 tiles). See round-6 notes.
// Row sums via ones-MFMA (32x32): the VALU ls-sum + permlane combine sat on
// the serial softmax chain while the MFMA pipe idled (r5: VALU 39% vs Mfma
// 13%); 4 MFMAs/tile are cheaper there and reduce cross-lane handling.
// Defer-max (THR=8): skip O-rescale when tile max doesn't grow.
// ---------------------------------------------------------------------------
__global__ __launch_bounds__(256, 4) void attn_kernel(
    const unsigned short* __restrict__ Qg, const unsigned short* __restrict__ Kg,
    const unsigned short* __restrict__ Vtg, unsigned short* __restrict__ Op0,
    unsigned short* __restrict__ Op1, float* __restrict__ mlb)
{
    __shared__ unsigned short Kl[2][64 * LK];
    __shared__ unsigned short Vl[2][64 * LK];

    const int tid  = threadIdx.x;
    const int w    = tid >> 6;
    const int lane = tid & 63;
    const int l31  = lane & 31;
    const int hi   = lane >> 5;

    const int bid  = blockIdx.x;
    const int x    = bid & 7;               // XCD under bid%8 round-robin
    const int j2   = (bid >> 3) & 3;
    const int jj   = (bid >> 5) & 7;
    const int q2   = (bid >> 8) & 3;
    const int bh   = (j2 << 3) | x;         // same-bh blocks share an XCD
    const int st   = (q2 & 1) ? (15 - jj) : jj;
    const int half = q2 >> 1;

    const int S0  = st << 7;             // block covers s in [S0, S0+128)
    const int sw  = S0 + 32 * w;         // wave's first query row
    const int s   = sw + l31;            // this lane's query row

    const unsigned short* Qb  = Qg  + (size_t)bh * SEQ * HD;
    const unsigned short* Kb  = Kg  + (size_t)bh * SEQ * HD;
    const unsigned short* Vtb = Vtg + (size_t)bh * HD * SEQ;

    // Q as B-operand: lane holds Q[s][16*kk + 8*hi + j]
    half8 bQ[4];
    {
        const unsigned short* qp = Qb + (size_t)s * HD + 8 * hi;
        #pragma unroll
        for (int kk = 0; kk < 4; ++kk)
            bQ[kk] = *(const half8*)(qp + 16 * kk);
    }

    half8 ones;
    #pragma unroll
    for (int j = 0; j < 8; ++j) ones[j] = (_Float16)1.0f;

    float m_run = -INFINITY, l_run = 0.f;
    floatx16 oT0 = zero16(), oT1 = zero16();   // O^T accum, d in [0,32) / [32,64)

    const int ztd  = (st << 1) + (w >> 1);   // wave's diagonal z-tile
    const int ntl  = st + 1;                 // tiles in this half
    const int zb   = half ? ntl : 0;         // first z-tile of this half
    const float L2E = 1.44269504f;

    // staging addresses: thread covers K row (srow+32*it), V row (srow+32*it)
    const int srow = tid >> 3, sc8 = (tid & 7) << 3;
    half8 kreg[2], vreg[2];

    // prologue: tile zb -> buf 0
    {
        const int z0 = zb << 6;
        #pragma unroll
        for (int it = 0; it < 2; ++it) {
            kreg[it] = *(const half8*)(Kb + (size_t)(z0 + srow + 32 * it) * HD + sc8);
            vreg[it] = *(const half8*)(Vtb + (size_t)(srow + 32 * it) * SEQ + z0 + sc8);
        }
        #pragma unroll
        for (int it = 0; it < 2; ++it) {
            *(half8*)(&Kl[0][(srow + 32 * it) * LK + sc8]) = kreg[it];
            *(half8*)(&Vl[0][(srow + 32 * it) * LK + sc8]) = vreg[it];
        }
    }

    int cur = 0;
    for (int zl = 0; zl < ntl; ++zl) {
        const int zt = zb + zl;
        const bool haveNext = (zl + 1 < ntl);
        const int z0n = (zt + 1) << 6;
        __syncthreads();                 // buf[cur] writes visible

        const unsigned short* Kc = Kl[cur];
        const unsigned short* Vc = Vl[cur];

        if (zt <= ztd) {
            const int z0 = zt << 6;
            // S^T = K @ Q^T : c0 covers z' in [0,32), c1 in [32,64); col = s
            floatx16 c0 = zero16(), c1 = zero16();
            #pragma unroll
            for (int kk = 0; kk < 4; ++kk) {
                half8 aK0 = *(const half8*)(&Kc[l31 * LK + 16 * kk + 8 * hi]);
                half8 aK1 = *(const half8*)(&Kc[(32 + l31) * LK + 16 * kk + 8 * hi]);
                c0 = __builtin_amdgcn_mfma_f32_32x32x16_f16(aK0, bQ[kk], c0, 0, 0, 0);
                c1 = __builtin_amdgcn_mfma_f32_32x32x16_f16(aK1, bQ[kk], c1, 0, 0, 0);
            }

            // prefetch next tile (issued here so HBM latency hides under
            // softmax + PV below)
            if (haveNext) {
                #pragma unroll
                for (int it = 0; it < 2; ++it) {
                    kreg[it] = *(const half8*)(Kb + (size_t)(z0n + srow + 32 * it) * HD + sc8);
                    vreg[it] = *(const half8*)(Vtb + (size_t)(srow + 32 * it) * SEQ + z0n + sc8);
                }
            }

            if (zt == ztd) {             // diagonal tile: mask z >= s
                float mval = (s == 0) ? 0.0f : -1e12f;
                #pragma unroll
                for (int r = 0; r < 16; ++r) {
                    int zl2 = (r & 3) + 8 * (r >> 2) + 4 * hi;
                    if (z0 + zl2      >= s) c0[r] = mval;
                    if (z0 + 32 + zl2 >= s) c1[r] = mval;
                }
            }

            // row max: balanced tree + one permlane32_swap
            float pm[8];
            #pragma unroll
            for (int rr = 0; rr < 8; ++rr)
                pm[rr] = fmaxf(fmaxf(c0[2 * rr], c0[2 * rr + 1]),
                               fmaxf(c1[2 * rr], c1[2 * rr + 1]));
            float rm = fmaxf(fmaxf(fmaxf(pm[0], pm[1]), fmaxf(pm[2], pm[3])),
                             fmaxf(fmaxf(pm[4], pm[5]), fmaxf(pm[6], pm[7])));
            {
                unsigned t0 = __builtin_bit_cast(unsigned, rm);
                unsigned t1 = t0;
                pl32(t0, t1);
                rm = fmaxf(__builtin_bit_cast(float, t0), __builtin_bit_cast(float, t1));
            }

            // defer-max: only rescale when running max grows by > THR=8
            if (!__all(rm <= m_run + 8.f)) {
                float mn = fmaxf(m_run, rm);
                float alpha = __expf(m_run - mn);
                m_run = mn;
                l_run *= alpha;
                #pragma unroll
                for (int r = 0; r < 16; ++r) { oT0[r] *= alpha; oT1[r] *= alpha; }
            }

            // p = exp(S - m_run) -> packed f16 pairs
            const float mb = m_run * L2E;
            unsigned pk0[8], pk1[8];
            #pragma unroll
            for (int t = 0; t < 8; ++t) {
                float a0 = __builtin_amdgcn_exp2f(fmaf(c0[2 * t],     L2E, -mb));
                float a1 = __builtin_amdgcn_exp2f(fmaf(c0[2 * t + 1], L2E, -mb));
                float b0 = __builtin_amdgcn_exp2f(fmaf(c1[2 * t],     L2E, -mb));
                float b1 = __builtin_amdgcn_exp2f(fmaf(c1[2 * t + 1], L2E, -mb));
                pk0[t] = __builtin_bit_cast(unsigned, __builtin_amdgcn_cvt_pkrtz(a0, a1));
                pk1[t] = __builtin_bit_cast(unsigned, __builtin_amdgcn_cvt_pkrtz(b0, b1));
            }
            // redistribute across lane halves: pk regs become B-frags in place
            pl32(pk0[0], pk0[2]); pl32(pk0[1], pk0[3]);
            pl32(pk0[4], pk0[6]); pl32(pk0[5], pk0[7]);
            pl32(pk1[0], pk1[2]); pl32(pk1[1], pk1[3]);
            pl32(pk1[4], pk1[6]); pl32(pk1[5], pk1[7]);
            half8 bP[4];
            bP[0] = bc4(pk0[0], pk0[1], pk0[2], pk0[3]);   // z in [ 0,16)
            bP[1] = bc4(pk0[4], pk0[5], pk0[6], pk0[7]);   // z in [16,32)
            bP[2] = bc4(pk1[0], pk1[1], pk1[2], pk1[3]);   // z in [32,48)
            bP[3] = bc4(pk1[4], pk1[5], pk1[6], pk1[7]);   // z in [48,64)

            // O^T += V^T @ P^T ; row sums via ones-MFMA on the same frags
            // (B's k spans both lane halves -> cross-lane sum is implicit)
            floatx16 lsa = zero16();
            #pragma unroll
            for (int kk = 0; kk < 4; ++kk) {
                half8 aV0 = *(const half8*)(&Vc[l31 * LK + 16 * kk + 8 * hi]);
                half8 aV1 = *(const half8*)(&Vc[(32 + l31) * LK + 16 * kk + 8 * hi]);
                oT0 = __builtin_amdgcn_mfma_f32_32x32x16_f16(aV0, bP[kk], oT0, 0, 0, 0);
                oT1 = __builtin_amdgcn_mfma_f32_32x32x16_f16(aV1, bP[kk], oT1, 0, 0, 0);
                lsa = __builtin_amdgcn_mfma_f32_32x32x16_f16(ones, bP[kk], lsa, 0, 0, 0);
            }
            l_run += lsa[0];
        } else {
            // fully-masked tile for this wave: still prefetch + commit
            if (haveNext) {
                #pragma unroll
                for (int it = 0; it < 2; ++it) {
                    kreg[it] = *(const half8*)(Kb + (size_t)(z0n + srow + 32 * it) * HD + sc8);
                    vreg[it] = *(const half8*)(Vtb + (size_t)(srow + 32 * it) * SEQ + z0n + sc8);
                }
            }
        }

        if (haveNext) {
            unsigned short* Kd = Kl[cur ^ 1];
            unsigned short* Vd = Vl[cur ^ 1];
            #pragma unroll
            for (int it = 0; it < 2; ++it) {
                *(half8*)(&Kd[(srow + 32 * it) * LK + sc8]) = kreg[it];
                *(half8*)(&Vd[(srow + 32 * it) * LK + sc8]) = vreg[it];
            }
        }
        cur ^= 1;
    }

    // epilogue: partial O (pre-normalized, f16) + (m, l) f32 for merge.
    // l_run==0 (fully-masked half) -> store zeros; m_run=-inf -> weight 0.
    float inv = (l_run > 0.f) ? (1.0f / l_run) : 0.f;
    unsigned short* Oph = half ? Op1 : Op0;
    unsigned short* op = Oph + ((size_t)bh * SEQ + s) * HD + 4 * hi;
    #pragma unroll
    for (int gg = 0; gg < 4; ++gg) {
        uint2 o0 = make_uint2(pk_f16(oT0[4 * gg + 0] * inv, oT0[4 * gg + 1] * inv),
                              pk_f16(oT0[4 * gg + 2] * inv, oT0[4 * gg + 3] * inv));
        *(uint2*)(op + 8 * gg) = o0;
        uint2 o1 = make_uint2(pk_f16(oT1[4 * gg + 0] * inv, oT1[4 * gg + 1] * inv),
                              pk_f16(oT1[4 * gg + 2] * inv, oT1[4 * gg + 3] * inv));
        *(uint2*)(op + 32 + 8 * gg) = o1;
    }
    if (hi == 0) {
        float* mlp = mlb + (((size_t)half * BH + bh) * SEQ + s) * 2;
        mlp[0] = m_run; mlp[1] = l_run;
    }
}

// ---------------------------------------------------------------------------
// Merge the two z-half partials:
// O = (e^{m1-m} l1 O1n + e^{m2-m} l2 O2n) / (e^{m1-m} l1 + e^{m2-m} l2).
// Skips s==0 (row0_kernel owns it). 4 threads/row, 16 d-elems each.
// ---------------------------------------------------------------------------
__global__ __launch_bounds__(256) void merge_kernel(
    const unsigned short* __restrict__ Op0, const unsigned short* __restrict__ Op1,
    const float* __restrict__ mlb, unsigned short* __restrict__ Og)
{
    const int tid  = threadIdx.x;
    const int blk  = blockIdx.x;            // 32 bh x 32 bands
    const int bh   = blk >> 5, band = blk & 31;
    const int r    = tid >> 2, dseg = (tid & 3) << 4;
    const int s    = (band << 6) | r;
    if (s == 0) return;                     // row0_kernel handles s==0

    const size_t row = (size_t)bh * SEQ + s;
    const float* mp0 = mlb + row * 2;
    const float* mp1 = mlb + ((size_t)BH * SEQ + row) * 2;
    float m1 = mp0[0], l1 = mp0[1];
    float m2 = mp1[0], l2 = mp1[1];
    float m  = fmaxf(m1, m2);
    float w1 = __expf(m1 - m) * l1;
    float w2 = __expf(m2 - m) * l2;
    float inv = 1.0f / (w1 + w2);           // l1 > 0 for all s >= 1
    w1 *= inv; w2 *= inv;

    const unsigned short* pa = Op0 + row * HD + dseg;
    const unsigned short* pc = Op1 + row * HD + dseg;
    half8 a0 = *(const half8*)(pa), a1 = *(const half8*)(pa + 8);
    half8 c0 = *(const half8*)(pc), c1 = *(const half8*)(pc + 8);

    float f[16];
    #pragma unroll
    for (int i = 0; i < 8; ++i) {
        f[i]     = w1 * (float)a0[i] + w2 * (float)c0[i];
        f[8 + i] = w1 * (float)a1[i] + w2 * (float)c1[i];
    }
    const int b = bh >> 4, h = bh & 15;
    unsigned short* og = Og + ((size_t)b * SEQ + s) * FDIM + h * HD + dseg;
    uint4 u0, u1;
    u0.x = pk_f16(f[0],  f[1]);  u0.y = pk_f16(f[2],  f[3]);
    u0.z = pk_f16(f[4],  f[5]);  u0.w = pk_f16(f[6],  f[7]);
    u1.x = pk_f16(f[8],  f[9]);  u1.y = pk_f16(f[10], f[11]);
    u1.z = pk_f16(f[12], f[13]); u1.w = pk_f16(f[14], f[15]);
    *(uint4*)og = u0;
    *(uint4*)(og + 8) = u1;
}

// ---------------------------------------------------------------------------
extern "C" void kernel_launch(void* const* d_in, const int* in_sizes, int n_in,
                              void* d_out, int out_size, void* d_ws, size_t ws_size,
                              hipStream_t stream) {
    const float* attend_from = (const float*)d_in[0];
    const float* attend_to   = (const float*)d_in[1];
    const float* w_q   = (const float*)d_in[2];
    const float* b_q   = (const float*)d_in[3];
    const float* w_kv  = (const float*)d_in[4];
    const float* b_kv  = (const float*)d_in[5];
    const float* w_out = (const float*)d_in[6];
    const float* b_out = (const float*)d_in[7];
    float* out = (float*)d_out;

    unsigned short* ws = (unsigned short*)d_ws;
    const size_t E = (size_t)(SB * SEQ) * FDIM;   // 4M elems
    unsigned short* Af   = ws;                    // reused: attn partial O half0
    unsigned short* At   = ws + E;                //         attn partial O half1
    unsigned short* Qb   = ws + 2 * E;
    unsigned short* Kb   = ws + 3 * E;
    unsigned short* Vb   = ws + 4 * E;
    unsigned short* Vt   = ws + 5 * E;
    unsigned short* Ob   = Vb;                    // reuse V after transpose
    unsigned short* Wqt  = ws + 6 * E;
    unsigned short* Wkvt = ws + 6 * E + E / 4;    // reused: attn (m,l) partials
    unsigned short* Wot  = ws + 6 * E + E / 4 + E / 2;
    float* mlb = (float*)Wkvt;                    // 2*BH*SEQ*2 f32 = 1.05 MB

    dim3 blk(256);
    const int M = SB * SEQ;   // 4096

    cvt_act<<<dim3(4096), blk, 0, stream>>>(attend_from, attend_to, Af, At);
    cvt_w<<<dim3(1024), blk, 0, stream>>>(w_q, w_kv, w_out, Wqt, Wkvt, Wot);
    gemm_qkv<<<dim3(24, M / 128), blk, 0, stream>>>(
        Af, At, Wqt, Wkvt, b_q, b_kv, Qb, Kb, Vb);
    transpose_v<<<dim3(BH * (SEQ / 64)), blk, 0, stream>>>(Vb, Vt);
    row0_kernel<<<dim3(BH), blk, 0, stream>>>(Vt, Ob);
    attn_kernel<<<dim3(BH * (SEQ / 128) * 2), blk, 0, stream>>>(
        Qb, Kb, Vt, Af, At, mlb);
    merge_kernel<<<dim3(BH * (SEQ / 64)), blk, 0, stream>>>(Af, At, mlb, Ob);
    gemm_out<<<dim3(FDIM / 128, M / 128), blk, 0, stream>>>(Ob, Wot, b_out, out);
}

// Round 8
// 207.404 us; speedup vs baseline: 1.0562x; 1.0562x over previous
//
#include <hip/hip_runtime.h>
#include <math.h>

#define SB   2
#define SEQ  2048
#define FDIM 1024
#define NH   16
#define HD   64
#define BH   (SB * NH)   // 32
#define LK   72          // attention LDS row stride in f16 elems (64 + 8 pad)

typedef _Float16 half8 __attribute__((ext_vector_type(8)));
typedef __attribute__((ext_vector_type(4))) float floatx4;
typedef __attribute__((ext_vector_type(16))) float floatx16;
typedef unsigned int uintx4 __attribute__((ext_vector_type(4)));
typedef unsigned int uint2v __attribute__((ext_vector_type(2)));

__device__ __forceinline__ unsigned pk_f16(float a, float b) {
    unsigned short ha = __builtin_bit_cast(unsigned short, (_Float16)a);
    unsigned short hb = __builtin_bit_cast(unsigned short, (_Float16)b);
    return (unsigned)ha | ((unsigned)hb << 16);
}
__device__ __forceinline__ unsigned short f16_1(float a) {
    _Float16 h = (_Float16)a;
    return __builtin_bit_cast(unsigned short, h);
}
__device__ __forceinline__ void load16_lds(const unsigned short* g, unsigned short* l) {
    __builtin_amdgcn_global_load_lds(
        (const __attribute__((address_space(1))) unsigned int*)g,
        (__attribute__((address_space(3))) unsigned int*)l, 16, 0, 0);
}
// hazard-safe permlane32_swap via builtin: swaps a.hi32lanes <-> b.lo32lanes
__device__ __forceinline__ void pl32(unsigned &a, unsigned &b) {
    uint2v r = __builtin_amdgcn_permlane32_swap(a, b, false, false);
    a = r[0]; b = r[1];
}
__device__ __forceinline__ half8 bc4(unsigned a, unsigned b, unsigned c, unsigned d) {
    uintx4 t; t[0] = a; t[1] = b; t[2] = c; t[3] = d;
    return __builtin_bit_cast(half8, t);
}
__device__ __forceinline__ floatx16 zero16() {
    floatx16 z;
    #pragma unroll
    for (int i = 0; i < 16; ++i) z[i] = 0.f;
    return z;
}

// ---------------------------------------------------------------------------
// fp32 -> f16: both activations in one launch. blockIdx.x < 2048 -> from.
// ---------------------------------------------------------------------------
__global__ __launch_bounds__(256) void cvt_act(
    const float* __restrict__ in0, const float* __restrict__ in1,
    unsigned short* __restrict__ out0, unsigned short* __restrict__ out1)
{
    int bx = blockIdx.x;
    const float* in = (bx < 2048) ? in0 : in1;
    unsigned short* out = (bx < 2048) ? out0 : out1;
    int i = ((bx & 2047) * 256 + threadIdx.x) * 8;
    float4 a = *(const float4*)(in + i);
    float4 b = *(const float4*)(in + i + 4);
    uint4 o;
    o.x = pk_f16(a.x, a.y); o.y = pk_f16(a.z, a.w);
    o.z = pk_f16(b.x, b.y); o.w = pk_f16(b.z, b.w);
    *(uint4*)(out + i) = o;
}

// ---------------------------------------------------------------------------
// All three W [K][N] fp32 -> Wt [N][K] f16 in one launch (64x64 LDS tiles).
// ---------------------------------------------------------------------------
__global__ __launch_bounds__(256) void cvt_w(
    const float* __restrict__ Wq, const float* __restrict__ Wkv,
    const float* __restrict__ Wo, unsigned short* __restrict__ Wqt,
    unsigned short* __restrict__ Wkvt, unsigned short* __restrict__ Wot)
{
    __shared__ float T[64 * 65];
    const int tid = threadIdx.x;
    int id = blockIdx.x;
    const float* W; unsigned short* Wt; int N, n0, k0;
    if (id < 256)      { W = Wq;  Wt = Wqt;  N = 1024; n0 = (id & 15) << 6; k0 = (id >> 4) << 6; }
    else if (id < 768) { id -= 256; W = Wkv; Wt = Wkvt; N = 2048; n0 = (id & 31) << 6; k0 = (id >> 5) << 6; }
    else               { id -= 768; W = Wo;  Wt = Wot;  N = 1024; n0 = (id & 15) << 6; k0 = (id >> 4) << 6; }

    #pragma unroll
    for (int i = 0; i < 4; ++i) {
        int idx = tid + (i << 8);
        int row = idx >> 4, c4 = idx & 15;
        float4 v = *(const float4*)(W + (size_t)(k0 + row) * N + n0 + (c4 << 2));
        float* tp = &T[row * 65 + (c4 << 2)];
        tp[0] = v.x; tp[1] = v.y; tp[2] = v.z; tp[3] = v.w;
    }
    __syncthreads();
    #pragma unroll
    for (int i = 0; i < 4; ++i) {
        int idx = tid + (i << 8);
        int n = idx >> 4, c4 = idx & 15;
        float x = T[(c4 * 4 + 0) * 65 + n];
        float y = T[(c4 * 4 + 1) * 65 + n];
        float z = T[(c4 * 4 + 2) * 65 + n];
        float w = T[(c4 * 4 + 3) * 65 + n];
        uint2 o = make_uint2(pk_f16(x, y), pk_f16(z, w));
        *(uint2*)(Wt + (size_t)(n0 + n) * FDIM + k0 + (c4 << 2)) = o;
    }
}

// ---------------------------------------------------------------------------
// f16 MFMA GEMM core (m97 structure): acc = A @ Wt^T, 128x128 tile, BK=32.
// (BK=64 + source-swizzle was tried in r7: regressed gemm_qkv 41->48 us;
//  reverted to this proven linear global_load_lds form.)
// ---------------------------------------------------------------------------
__device__ __forceinline__ void gemm_core(
    const unsigned short* __restrict__ A, const unsigned short* __restrict__ Wt,
    int m0, int n0, int K, floatx4 (&acc)[4][4],
    unsigned short* Al, unsigned short* Bl)
{
    const int tid  = threadIdx.x;
    const int w    = tid >> 6;
    const int lane = tid & 63;
    const int q    = lane >> 4, l = lane & 15;
    const int wm = (w >> 1) * 64, wn = (w & 1) * 64;

    for (int k0 = 0; k0 < K; k0 += 32) {
        __syncthreads();
        #pragma unroll
        for (int it = 0; it < 2; ++it) {
            int c = (w * 2 + it) * 64 + lane;
            int row = c >> 2, o = (c & 3) * 8;
            load16_lds(A  + (size_t)(m0 + row) * K + k0 + o, Al + c * 8);
            load16_lds(Wt + (size_t)(n0 + row) * K + k0 + o, Bl + c * 8);
        }
        __syncthreads();

        half8 aF[4], bF[4];
        #pragma unroll
        for (int i = 0; i < 4; ++i)
            aF[i] = *(const half8*)(Al + (wm + 16 * i + l) * 32 + 8 * q);
        #pragma unroll
        for (int j = 0; j < 4; ++j)
            bF[j] = *(const half8*)(Bl + (wn + 16 * j + l) * 32 + 8 * q);
        #pragma unroll
        for (int i = 0; i < 4; ++i)
            #pragma unroll
            for (int j = 0; j < 4; ++j)
                acc[i][j] = __builtin_amdgcn_mfma_f32_16x16x32_f16(
                    aF[i], bF[j], acc[i][j], 0, 0, 0);
    }
}

// ---------------------------------------------------------------------------
// Merged Q + KV projection GEMM, 1-D grid 768.
// XCD-affine mapping: xcd=bid&7; each XCD owns m-tiles {4*xcd..4*xcd+3}
// (A panels 2 MB, L2-resident) x all 24 n-tiles (W streamed; the 4 co-XCD
// blocks sharing a W-panel are dispatched consecutively -> L2 temporal hit).
// Each A-panel is HBM-fetched by exactly ONE XCD (r7: 71.7 MB over-fetch).
// V output (bx>=16, block-uniform) is written TRANSPOSED directly into
// Vt[bh][d][z] (4 consecutive s -> one uint2) -> transpose_v kernel deleted.
// ---------------------------------------------------------------------------
__global__ __launch_bounds__(256) void gemm_qkv(
    const unsigned short* __restrict__ Af, const unsigned short* __restrict__ At,
    const unsigned short* __restrict__ Wqt, const unsigned short* __restrict__ Wkvt,
    const float* __restrict__ bq, const float* __restrict__ bkv,
    unsigned short* __restrict__ Qo, unsigned short* __restrict__ Ko,
    unsigned short* __restrict__ Vt)
{
    __shared__ unsigned short Al[128 * 32];
    __shared__ unsigned short Bl[128 * 32];

    const int tid  = threadIdx.x;
    const int w    = tid >> 6;
    const int lane = tid & 63;
    const int q    = lane >> 4, l = lane & 15;
    const int wm = (w >> 1) * 64, wn = (w & 1) * 64;

    const int bid = blockIdx.x;
    const int xcd = bid & 7;
    const int idx = bid >> 3;                 // 0..95
    const int bx  = idx >> 2;                 // 0..23 (n-tile)
    const int by  = (idx & 3) + (xcd << 2);   // 0..31 (m-tile)
    const int m0  = by * 128;

    bool isQ = bx < 8;
    const unsigned short* A  = isQ ? Af : At;
    const unsigned short* Wt = isQ ? Wqt : Wkvt;
    const float* bias        = isQ ? bq : bkv;
    const int n0 = (isQ ? bx : (bx - 8)) * 128;

    floatx4 acc[4][4];
    #pragma unroll
    for (int i = 0; i < 4; ++i)
        #pragma unroll
        for (int j = 0; j < 4; ++j)
            acc[i][j] = (floatx4){0.f, 0.f, 0.f, 0.f};

    gemm_core(A, Wt, m0, n0, FDIM, acc, Al, Bl);

    float bj[4];
    #pragma unroll
    for (int j = 0; j < 4; ++j) bj[j] = bias[n0 + wn + 16 * j + l];

    #pragma unroll
    for (int i = 0; i < 4; ++i)
        #pragma unroll
        for (int j = 0; j < 4; ++j) {
            int n = n0 + wn + 16 * j + l;
            float vv[4];
            #pragma unroll
            for (int r = 0; r < 4; ++r) vv[r] = acc[i][j][r] + bj[j];
            int mm = m0 + wm + 16 * i + 4 * q;     // s of r=0 (4-aligned run)
            int b = mm >> 11, s0 = mm & (SEQ - 1);
            if (isQ) {
                int h = n >> 6, dd = n & 63;
                unsigned short* qp = Qo + ((size_t)(b * NH + h) * SEQ + s0) * HD + dd;
                #pragma unroll
                for (int r = 0; r < 4; ++r) qp[r * HD] = f16_1(vv[r]);
            } else if (n < FDIM) {                 // K (block-uniform branch)
                int h = n >> 6, dd = n & 63;
                unsigned short* kp = Ko + ((size_t)(b * NH + h) * SEQ + s0) * HD + dd;
                #pragma unroll
                for (int r = 0; r < 4; ++r) kp[r * HD] = f16_1(vv[r]);
            } else {                               // V -> transposed layout
                int np = n - FDIM;
                int h = np >> 6, dd = np & 63;
                uint2 o = make_uint2(pk_f16(vv[0], vv[1]), pk_f16(vv[2], vv[3]));
                *(uint2*)(Vt + ((size_t)(b * NH + h) * HD + dd) * SEQ + s0) = o;
            }
        }
}

// ---------------------------------------------------------------------------
// Out-projection GEMM: fp32 output [M][N]. 1-D grid 256, XCD-affine mapping
// (each XCD owns m-tiles {4*xcd..4*xcd+3} x all 8 n-tiles).
// ---------------------------------------------------------------------------
__global__ __launch_bounds__(256) void gemm_out(
    const unsigned short* __restrict__ A, const unsigned short* __restrict__ Wt,
    const float* __restrict__ bias, float* __restrict__ C)
{
    __shared__ unsigned short Al[128 * 32];
    __shared__ unsigned short Bl[128 * 32];

    const int tid  = threadIdx.x;
    const int w    = tid >> 6;
    const int lane = tid & 63;
    const int q    = lane >> 4, l = lane & 15;
    const int wm = (w >> 1) * 64, wn = (w & 1) * 64;

    const int bid = blockIdx.x;
    const int xcd = bid & 7;
    const int idx = bid >> 3;                 // 0..31
    const int bx  = idx >> 2;                 // 0..7 (n-tile)
    const int by  = (idx & 3) + (xcd << 2);   // 0..31 (m-tile)
    const int m0 = by * 128, n0 = bx * 128;

    floatx4 acc[4][4];
    #pragma unroll
    for (int i = 0; i < 4; ++i)
        #pragma unroll
        for (int j = 0; j < 4; ++j)
            acc[i][j] = (floatx4){0.f, 0.f, 0.f, 0.f};

    gemm_core(A, Wt, m0, n0, FDIM, acc, Al, Bl);

    float bj[4];
    #pragma unroll
    for (int j = 0; j < 4; ++j) bj[j] = bias[n0 + wn + 16 * j + l];

    #pragma unroll
    for (int i = 0; i < 4; ++i)
        #pragma unroll
        for (int j = 0; j < 4; ++j) {
            int n = n0 + wn + 16 * j + l;
            #pragma unroll
            for (int r = 0; r < 4; ++r) {
                int m = m0 + wm + 16 * i + 4 * q + r;
                C[(size_t)m * FDIM + n] = acc[i][j][r] + bj[j];
            }
        }
}

// ---------------------------------------------------------------------------
// Row s=0 of each (b,h): reference's fully-masked row -> uniform softmax over
// all 2048 columns -> O[b,0,h*64+d] = mean_z V[bh][z][d]. Writes Og row 0
// (merge_kernel skips s==0).
// ---------------------------------------------------------------------------
__global__ __launch_bounds__(256) void row0_kernel(
    const unsigned short* __restrict__ Vtg, unsigned short* __restrict__ Og)
{
    __shared__ float red[256];
    const int bh = blockIdx.x;
    const int tid = threadIdx.x;
    const int d = tid >> 2, part = tid & 3;
    const unsigned short* vp = Vtg + ((size_t)bh * HD + d) * SEQ + part * 512;
    float s = 0.f;
    #pragma unroll
    for (int i = 0; i < 64; ++i) {
        half8 v = *(const half8*)(vp + i * 8);
        #pragma unroll
        for (int j = 0; j < 8; ++j) s += (float)v[j];
    }
    red[tid] = s;
    __syncthreads();
    if (part == 0) {
        float t = red[tid] + red[tid + 1] + red[tid + 2] + red[tid + 3];
        const int b = bh >> 4, h = bh & 15;
        Og[(size_t)b * SEQ * FDIM + h * HD + d] = f16_1(t * (1.0f / 2048.0f));
    }
}

// ---------------------------------------------------------------------------
// Flash attention, swapped-operand 32x32x16 MFMA, in-register softmax (T12),
// z-SPLIT for occupancy (1024 blocks = 4 blocks/CU). Partial O + (m,l);
// merge_kernel combines.
// Block mapping: XCD affinity (same-bh blocks share bid%8) + CU balance
// (co-resident quads stage exactly 34 tiles).
// Row sums via ones-MFMA (32x32). Defer-max THR=8.
// ---------------------------------------------------------------------------
__global__ __launch_bounds__(256, 4) void attn_kernel(
    const unsigned short* __restrict__ Qg, const unsigned short* __restrict__ Kg,
    const unsigned short* __restrict__ Vtg, unsigned short* __restrict__ Op0,
    unsigned short* __restrict__ Op1, float* __restrict__ mlb)
{
    __shared__ unsigned short Kl[2][64 * LK];
    __shared__ unsigned short Vl[2][64 * LK];

    const int tid  = threadIdx.x;
    const int w    = tid >> 6;
    const int lane = tid & 63;
    const int l31  = lane & 31;
    const int hi   = lane >> 5;

    const int bid  = blockIdx.x;
    const int x    = bid & 7;               // XCD under bid%8 round-robin
    const int j2   = (bid >> 3) & 3;
    const int jj   = (bid >> 5) & 7;
    const int q2   = (bid >> 8) & 3;
    const int bh   = (j2 << 3) | x;         // same-bh blocks share an XCD
    const int st   = (q2 & 1) ? (15 - jj) : jj;
    const int half = q2 >> 1;

    const int S0  = st << 7;             // block covers s in [S0, S0+128)
    const int sw  = S0 + 32 * w;         // wave's first query row
    const int s   = sw + l31;            // this lane's query row

    const unsigned short* Qb  = Qg  + (size_t)bh * SEQ * HD;
    const unsigned short* Kb  = Kg  + (size_t)bh * SEQ * HD;
    const unsigned short* Vtb = Vtg + (size_t)bh * HD * SEQ;

    // Q as B-operand: lane holds Q[s][16*kk + 8*hi + j]
    half8 bQ[4];
    {
        const unsigned short* qp = Qb + (size_t)s * HD + 8 * hi;
        #pragma unroll
        for (int kk = 0; kk < 4; ++kk)
            bQ[kk] = *(const half8*)(qp + 16 * kk);
    }

    half8 ones;
    #pragma unroll
    for (int j = 0; j < 8; ++j) ones[j] = (_Float16)1.0f;

    float m_run = -INFINITY, l_run = 0.f;
    floatx16 oT0 = zero16(), oT1 = zero16();   // O^T accum, d in [0,32) / [32,64)

    const int ztd  = (st << 1) + (w >> 1);   // wave's diagonal z-tile
    const int ntl  = st + 1;                 // tiles in this half
    const int zb   = half ? ntl : 0;         // first z-tile of this half
    const float L2E = 1.44269504f;

    // staging addresses: thread covers K row (srow+32*it), V row (srow+32*it)
    const int srow = tid >> 3, sc8 = (tid & 7) << 3;
    half8 kreg[2], vreg[2];

    // prologue: tile zb -> buf 0
    {
        const int z0 = zb << 6;
        #pragma unroll
        for (int it = 0; it < 2; ++it) {
            kreg[it] = *(const half8*)(Kb + (size_t)(z0 + srow + 32 * it) * HD + sc8);
            vreg[it] = *(const half8*)(Vtb + (size_t)(srow + 32 * it) * SEQ + z0 + sc8);
        }
        #pragma unroll
        for (int it = 0; it < 2; ++it) {
            *(half8*)(&Kl[0][(srow + 32 * it) * LK + sc8]) = kreg[it];
            *(half8*)(&Vl[0][(srow + 32 * it) * LK + sc8]) = vreg[it];
        }
    }

    int cur = 0;
    for (int zl = 0; zl < ntl; ++zl) {
        const int zt = zb + zl;
        const bool haveNext = (zl + 1 < ntl);
        const int z0n = (zt + 1) << 6;
        __syncthreads();                 // buf[cur] writes visible

        const unsigned short* Kc = Kl[cur];
        const unsigned short* Vc = Vl[cur];

        if (zt <= ztd) {
            const int z0 = zt << 6;
            // S^T = K @ Q^T : c0 covers z' in [0,32), c1 in [32,64); col = s
            floatx16 c0 = zero16(), c1 = zero16();
            #pragma unroll
            for (int kk = 0; kk < 4; ++kk) {
                half8 aK0 = *(const half8*)(&Kc[l31 * LK + 16 * kk + 8 * hi]);
                half8 aK1 = *(const half8*)(&Kc[(32 + l31) * LK + 16 * kk + 8 * hi]);
                c0 = __builtin_amdgcn_mfma_f32_32x32x16_f16(aK0, bQ[kk], c0, 0, 0, 0);
                c1 = __builtin_amdgcn_mfma_f32_32x32x16_f16(aK1, bQ[kk], c1, 0, 0, 0);
            }

            // prefetch next tile (issued here so HBM latency hides under
            // softmax + PV below)
            if (haveNext) {
                #pragma unroll
                for (int it = 0; it < 2; ++it) {
                    kreg[it] = *(const half8*)(Kb + (size_t)(z0n + srow + 32 * it) * HD + sc8);
                    vreg[it] = *(const half8*)(Vtb + (size_t)(srow + 32 * it) * SEQ + z0n + sc8);
                }
            }

            if (zt == ztd) {             // diagonal tile: mask z >= s
                float mval = (s == 0) ? 0.0f : -1e12f;
                #pragma unroll
                for (int r = 0; r < 16; ++r) {
                    int zl2 = (r & 3) + 8 * (r >> 2) + 4 * hi;
                    if (z0 + zl2      >= s) c0[r] = mval;
                    if (z0 + 32 + zl2 >= s) c1[r] = mval;
                }
            }

            // row max: balanced tree + one permlane32_swap
            float pm[8];
            #pragma unroll
            for (int rr = 0; rr < 8; ++rr)
                pm[rr] = fmaxf(fmaxf(c0[2 * rr], c0[2 * rr + 1]),
                               fmaxf(c1[2 * rr], c1[2 * rr + 1]));
            float rm = fmaxf(fmaxf(fmaxf(pm[0], pm[1]), fmaxf(pm[2], pm[3])),
                             fmaxf(fmaxf(pm[4], pm[5]), fmaxf(pm[6], pm[7])));
            {
                unsigned t0 = __builtin_bit_cast(unsigned, rm);
                unsigned t1 = t0;
                pl32(t0, t1);
                rm = fmaxf(__builtin_bit_cast(float, t0), __builtin_bit_cast(float, t1));
            }

            // defer-max: only rescale when running max grows by > THR=8
            if (!__all(rm <= m_run + 8.f)) {
                float mn = fmaxf(m_run, rm);
                float alpha = __expf(m_run - mn);
                m_run = mn;
                l_run *= alpha;
                #pragma unroll
                for (int r = 0; r < 16; ++r) { oT0[r] *= alpha; oT1[r] *= alpha; }
            }

            // p = exp(S - m_run) -> packed f16 pairs
            const float mb = m_run * L2E;
            unsigned pk0[8], pk1[8];
            #pragma unroll
            for (int t = 0; t < 8; ++t) {
                float a0 = __builtin_amdgcn_exp2f(fmaf(c0[2 * t],     L2E, -mb));
                float a1 = __builtin_amdgcn_exp2f(fmaf(c0[2 * t + 1], L2E, -mb));
                float b0 = __builtin_amdgcn_exp2f(fmaf(c1[2 * t],     L2E, -mb));
                float b1 = __builtin_amdgcn_exp2f(fmaf(c1[2 * t + 1], L2E, -mb));
                pk0[t] = __builtin_bit_cast(unsigned, __builtin_amdgcn_cvt_pkrtz(a0, a1));
                pk1[t] = __builtin_bit_cast(unsigned, __builtin_amdgcn_cvt_pkrtz(b0, b1));
            }
            // redistribute across lane halves: pk regs become B-frags in place
            pl32(pk0[0], pk0[2]); pl32(pk0[1], pk0[3]);
            pl32(pk0[4], pk0[6]); pl32(pk0[5], pk0[7]);
            pl32(pk1[0], pk1[2]); pl32(pk1[1], pk1[3]);
            pl32(pk1[4], pk1[6]); pl32(pk1[5], pk1[7]);
            half8 bP[4];
            bP[0] = bc4(pk0[0], pk0[1], pk0[2], pk0[3]);   // z in [ 0,16)
            bP[1] = bc4(pk0[4], pk0[5], pk0[6], pk0[7]);   // z in [16,32)
            bP[2] = bc4(pk1[0], pk1[1], pk1[2], pk1[3]);   // z in [32,48)
            bP[3] = bc4(pk1[4], pk1[5], pk1[6], pk1[7]);   // z in [48,64)

            // O^T += V^T @ P^T ; row sums via ones-MFMA on the same frags
            floatx16 lsa = zero16();
            #pragma unroll
            for (int kk = 0; kk < 4; ++kk) {
                half8 aV0 = *(const half8*)(&Vc[l31 * LK + 16 * kk + 8 * hi]);
                half8 aV1 = *(const half8*)(&Vc[(32 + l31) * LK + 16 * kk + 8 * hi]);
                oT0 = __builtin_amdgcn_mfma_f32_32x32x16_f16(aV0, bP[kk], oT0, 0, 0, 0);
                oT1 = __builtin_amdgcn_mfma_f32_32x32x16_f16(aV1, bP[kk], oT1, 0, 0, 0);
                lsa = __builtin_amdgcn_mfma_f32_32x32x16_f16(ones, bP[kk], lsa, 0, 0, 0);
            }
            l_run += lsa[0];
        } else {
            // fully-masked tile for this wave: still prefetch + commit
            if (haveNext) {
                #pragma unroll
                for (int it = 0; it < 2; ++it) {
                    kreg[it] = *(const half8*)(Kb + (size_t)(z0n + srow + 32 * it) * HD + sc8);
                    vreg[it] = *(const half8*)(Vtb + (size_t)(srow + 32 * it) * SEQ + z0n + sc8);
                }
            }
        }

        if (haveNext) {
            unsigned short* Kd = Kl[cur ^ 1];
            unsigned short* Vd = Vl[cur ^ 1];
            #pragma unroll
            for (int it = 0; it < 2; ++it) {
                *(half8*)(&Kd[(srow + 32 * it) * LK + sc8]) = kreg[it];
                *(half8*)(&Vd[(srow + 32 * it) * LK + sc8]) = vreg[it];
            }
        }
        cur ^= 1;
    }

    // epilogue: partial O (pre-normalized, f16) + (m, l) f32 for merge.
    // l_run==0 (fully-masked half) -> store zeros; m_run=-inf -> weight 0.
    float inv = (l_run > 0.f) ? (1.0f / l_run) : 0.f;
    unsigned short* Oph = half ? Op1 : Op0;
    unsigned short* op = Oph + ((size_t)bh * SEQ + s) * HD + 4 * hi;
    #pragma unroll
    for (int gg = 0; gg < 4; ++gg) {
        uint2 o0 = make_uint2(pk_f16(oT0[4 * gg + 0] * inv, oT0[4 * gg + 1] * inv),
                              pk_f16(oT0[4 * gg + 2] * inv, oT0[4 * gg + 3] * inv));
        *(uint2*)(op + 8 * gg) = o0;
        uint2 o1 = make_uint2(pk_f16(oT1[4 * gg + 0] * inv, oT1[4 * gg + 1] * inv),
                              pk_f16(oT1[4 * gg + 2] * inv, oT1[4 * gg + 3] * inv));
        *(uint2*)(op + 32 + 8 * gg) = o1;
    }
    if (hi == 0) {
        float* mlp = mlb + (((size_t)half * BH + bh) * SEQ + s) * 2;
        mlp[0] = m_run; mlp[1] = l_run;
    }
}

// ---------------------------------------------------------------------------
// Merge the two z-half partials:
// O = (e^{m1-m} l1 O1n + e^{m2-m} l2 O2n) / (e^{m1-m} l1 + e^{m2-m} l2).
// Skips s==0 (row0_kernel owns it). 4 threads/row, 16 d-elems each.
// ---------------------------------------------------------------------------
__global__ __launch_bounds__(256) void merge_kernel(
    const unsigned short* __restrict__ Op0, const unsigned short* __restrict__ Op1,
    const float* __restrict__ mlb, unsigned short* __restrict__ Og)
{
    const int tid  = threadIdx.x;
    const int blk  = blockIdx.x;            // 32 bh x 32 bands
    const int bh   = blk >> 5, band = blk & 31;
    const int r    = tid >> 2, dseg = (tid & 3) << 4;
    const int s    = (band << 6) | r;
    if (s == 0) return;                     // row0_kernel handles s==0

    const size_t row = (size_t)bh * SEQ + s;
    const float* mp0 = mlb + row * 2;
    const float* mp1 = mlb + ((size_t)BH * SEQ + row) * 2;
    float m1 = mp0[0], l1 = mp0[1];
    float m2 = mp1[0], l2 = mp1[1];
    float m  = fmaxf(m1, m2);
    float w1 = __expf(m1 - m) * l1;
    float w2 = __expf(m2 - m) * l2;
    float inv = 1.0f / (w1 + w2);           // l1 > 0 for all s >= 1
    w1 *= inv; w2 *= inv;

    const unsigned short* pa = Op0 + row * HD + dseg;
    const unsigned short* pc = Op1 + row * HD + dseg;
    half8 a0 = *(const half8*)(pa), a1 = *(const half8*)(pa + 8);
    half8 c0 = *(const half8*)(pc), c1 = *(const half8*)(pc + 8);

    float f[16];
    #pragma unroll
    for (int i = 0; i < 8; ++i) {
        f[i]     = w1 * (float)a0[i] + w2 * (float)c0[i];
        f[8 + i] = w1 * (float)a1[i] + w2 * (float)c1[i];
    }
    const int b = bh >> 4, h = bh & 15;
    unsigned short* og = Og + ((size_t)b * SEQ + s) * FDIM + h * HD + dseg;
    uint4 u0, u1;
    u0.x = pk_f16(f[0],  f[1]);  u0.y = pk_f16(f[2],  f[3]);
    u0.z = pk_f16(f[4],  f[5]);  u0.w = pk_f16(f[6],  f[7]);
    u1.x = pk_f16(f[8],  f[9]);  u1.y = pk_f16(f[10], f[11]);
    u1.z = pk_f16(f[12], f[13]); u1.w = pk_f16(f[14], f[15]);
    *(uint4*)og = u0;
    *(uint4*)(og + 8) = u1;
}

// ---------------------------------------------------------------------------
extern "C" void kernel_launch(void* const* d_in, const int* in_sizes, int n_in,
                              void* d_out, int out_size, void* d_ws, size_t ws_size,
                              hipStream_t stream) {
    const float* attend_from = (const float*)d_in[0];
    const float* attend_to   = (const float*)d_in[1];
    const float* w_q   = (const float*)d_in[2];
    const float* b_q   = (const float*)d_in[3];
    const float* w_kv  = (const float*)d_in[4];
    const float* b_kv  = (const float*)d_in[5];
    const float* w_out = (const float*)d_in[6];
    const float* b_out = (const float*)d_in[7];
    float* out = (float*)d_out;

    unsigned short* ws = (unsigned short*)d_ws;
    const size_t E = (size_t)(SB * SEQ) * FDIM;   // 4M elems
    unsigned short* Af   = ws;                    // reused: attn partial O half0
    unsigned short* At   = ws + E;                //         attn partial O half1
    unsigned short* Qb   = ws + 2 * E;
    unsigned short* Kb   = ws + 3 * E;
    unsigned short* Ob   = ws + 4 * E;            // attn output (A of out-GEMM)
    unsigned short* Vt   = ws + 5 * E;            // V written transposed by gemm_qkv
    unsigned short* Wqt  = ws + 6 * E;
    unsigned short* Wkvt = ws + 6 * E + E / 4;
    unsigned short* Wot  = ws + 6 * E + E / 4 + E / 2;
    float* mlb = (float*)Wkvt;                    // reused after gemm_qkv; 1.05 MB

    dim3 blk(256);
    const int M = SB * SEQ;   // 4096

    cvt_act<<<dim3(4096), blk, 0, stream>>>(attend_from, attend_to, Af, At);
    cvt_w<<<dim3(1024), blk, 0, stream>>>(w_q, w_kv, w_out, Wqt, Wkvt, Wot);
    gemm_qkv<<<dim3(768), blk, 0, stream>>>(
        Af, At, Wqt, Wkvt, b_q, b_kv, Qb, Kb, Vt);
    row0_kernel<<<dim3(BH), blk, 0, stream>>>(Vt, Ob);
    attn_kernel<<<dim3(BH * (SEQ / 128) * 2), blk, 0, stream>>>(
        Qb, Kb, Vt, Af, At, mlb);
    merge_kernel<<<dim3(BH * (SEQ / 64)), blk, 0, stream>>>(Af, At, mlb, Ob);
    gemm_out<<<dim3(256), blk, 0, stream>>>(Ob, Wot, b_out, out);
}

// Round 9
// 203.141 us; speedup vs baseline: 1.0784x; 1.0210x over previous
//
#include <hip/hip_runtime.h>
#include <math.h>

#define SB   2
#define SEQ  2048
#define FDIM 1024
#define NH   16
#define HD   64
#define BH   (SB * NH)   // 32
#define LK   72          // attention LDS row stride in f16 elems (64 + 8 pad)

typedef _Float16 half8 __attribute__((ext_vector_type(8)));
typedef __attribute__((ext_vector_type(4))) float floatx4;
typedef __attribute__((ext_vector_type(16))) float floatx16;
typedef unsigned int uintx4 __attribute__((ext_vector_type(4)));
typedef unsigned int uint2v __attribute__((ext_vector_type(2)));

__device__ __forceinline__ unsigned pk_f16(float a, float b) {
    unsigned short ha = __builtin_bit_cast(unsigned short, (_Float16)a);
    unsigned short hb = __builtin_bit_cast(unsigned short, (_Float16)b);
    return (unsigned)ha | ((unsigned)hb << 16);
}
__device__ __forceinline__ unsigned short f16_1(float a) {
    _Float16 h = (_Float16)a;
    return __builtin_bit_cast(unsigned short, h);
}
__device__ __forceinline__ void load16_lds(const unsigned short* g, unsigned short* l) {
    __builtin_amdgcn_global_load_lds(
        (const __attribute__((address_space(1))) unsigned int*)g,
        (__attribute__((address_space(3))) unsigned int*)l, 16, 0, 0);
}
// hazard-safe permlane32_swap via builtin: swaps a.hi32lanes <-> b.lo32lanes
__device__ __forceinline__ void pl32(unsigned &a, unsigned &b) {
    uint2v r = __builtin_amdgcn_permlane32_swap(a, b, false, false);
    a = r[0]; b = r[1];
}
__device__ __forceinline__ half8 bc4(unsigned a, unsigned b, unsigned c, unsigned d) {
    uintx4 t; t[0] = a; t[1] = b; t[2] = c; t[3] = d;
    return __builtin_bit_cast(half8, t);
}
__device__ __forceinline__ floatx16 zero16() {
    floatx16 z;
    #pragma unroll
    for (int i = 0; i < 16; ++i) z[i] = 0.f;
    return z;
}

// ---------------------------------------------------------------------------
// Combined precompute: blocks [0,4096) convert activations fp32->f16;
// blocks [4096,5120) transpose+convert the three weight matrices.
// One launch removes a serialization gap between the two former kernels.
// ---------------------------------------------------------------------------
__global__ __launch_bounds__(256) void cvt_all(
    const float* __restrict__ in0, const float* __restrict__ in1,
    unsigned short* __restrict__ out0, unsigned short* __restrict__ out1,
    const float* __restrict__ Wq, const float* __restrict__ Wkv,
    const float* __restrict__ Wo, unsigned short* __restrict__ Wqt,
    unsigned short* __restrict__ Wkvt, unsigned short* __restrict__ Wot)
{
    __shared__ float T[64 * 65];
    const int tid = threadIdx.x;
    int bid = blockIdx.x;

    if (bid < 4096) {               // activation convert path (no LDS use)
        const float* in = (bid < 2048) ? in0 : in1;
        unsigned short* out = (bid < 2048) ? out0 : out1;
        int i = ((bid & 2047) * 256 + tid) * 8;
        float4 a = *(const float4*)(in + i);
        float4 b = *(const float4*)(in + i + 4);
        uint4 o;
        o.x = pk_f16(a.x, a.y); o.y = pk_f16(a.z, a.w);
        o.z = pk_f16(b.x, b.y); o.w = pk_f16(b.z, b.w);
        *(uint4*)(out + i) = o;
        return;
    }

    int id = bid - 4096;            // weight transpose path
    const float* W; unsigned short* Wt; int N, n0, k0;
    if (id < 256)      { W = Wq;  Wt = Wqt;  N = 1024; n0 = (id & 15) << 6; k0 = (id >> 4) << 6; }
    else if (id < 768) { id -= 256; W = Wkv; Wt = Wkvt; N = 2048; n0 = (id & 31) << 6; k0 = (id >> 5) << 6; }
    else               { id -= 768; W = Wo;  Wt = Wot;  N = 1024; n0 = (id & 15) << 6; k0 = (id >> 4) << 6; }

    #pragma unroll
    for (int i = 0; i < 4; ++i) {
        int idx = tid + (i << 8);
        int row = idx >> 4, c4 = idx & 15;
        float4 v = *(const float4*)(W + (size_t)(k0 + row) * N + n0 + (c4 << 2));
        float* tp = &T[row * 65 + (c4 << 2)];
        tp[0] = v.x; tp[1] = v.y; tp[2] = v.z; tp[3] = v.w;
    }
    __syncthreads();
    #pragma unroll
    for (int i = 0; i < 4; ++i) {
        int idx = tid + (i << 8);
        int n = idx >> 4, c4 = idx & 15;
        float x = T[(c4 * 4 + 0) * 65 + n];
        float y = T[(c4 * 4 + 1) * 65 + n];
        float z = T[(c4 * 4 + 2) * 65 + n];
        float w = T[(c4 * 4 + 3) * 65 + n];
        uint2 o = make_uint2(pk_f16(x, y), pk_f16(z, w));
        *(uint2*)(Wt + (size_t)(n0 + n) * FDIM + k0 + (c4 << 2)) = o;
    }
}

// ---------------------------------------------------------------------------
// f16 MFMA GEMM core, 128x128 tile, BK=32, DOUBLE-BUFFERED LDS (T3-minimum):
// per K-step, one barrier drains the loads staged LAST step, then next-tile
// global_load_lds is issued into the other buffer BEFORE ds_read+MFMA of the
// current tile -> HBM/L2 latency hides under compute (was fully exposed in
// the single-buffered form: barrier-stage-barrier-compute).
// Race-free: the barrier's lgkmcnt(0) also guarantees all prior ds_reads of
// the write-target buffer completed. Al/Bl are [2][128*32].
// ---------------------------------------------------------------------------
__device__ __forceinline__ void gemm_core(
    const unsigned short* __restrict__ A, const unsigned short* __restrict__ Wt,
    int m0, int n0, int K, floatx4 (&acc)[4][4],
    unsigned short* Al, unsigned short* Bl)
{
    const int tid  = threadIdx.x;
    const int w    = tid >> 6;
    const int lane = tid & 63;
    const int q    = lane >> 4, l = lane & 15;
    const int wm = (w >> 1) * 64, wn = (w & 1) * 64;

    const int c   = (w * 2) * 64 + lane;      // this thread's chunk (it=0)
    const int c2  = c + 64;                   // it=1
    const int r0 = c >> 2,  o0 = (c & 3) * 8;
    const int r1 = c2 >> 2, o1 = (c2 & 3) * 8;

    // prologue: tile 0 -> buf 0
    load16_lds(A  + (size_t)(m0 + r0) * K + o0, Al + c * 8);
    load16_lds(Wt + (size_t)(n0 + r0) * K + o0, Bl + c * 8);
    load16_lds(A  + (size_t)(m0 + r1) * K + o1, Al + c2 * 8);
    load16_lds(Wt + (size_t)(n0 + r1) * K + o1, Bl + c2 * 8);

    int cur = 0;
    for (int k0 = 0; k0 < K; k0 += 32) {
        __syncthreads();                      // buf[cur] loaded & visible
        if (k0 + 32 < K) {                    // issue next tile -> buf[cur^1]
            int nb = (cur ^ 1) * 4096;
            load16_lds(A  + (size_t)(m0 + r0) * K + k0 + 32 + o0, Al + nb + c * 8);
            load16_lds(Wt + (size_t)(n0 + r0) * K + k0 + 32 + o0, Bl + nb + c * 8);
            load16_lds(A  + (size_t)(m0 + r1) * K + k0 + 32 + o1, Al + nb + c2 * 8);
            load16_lds(Wt + (size_t)(n0 + r1) * K + k0 + 32 + o1, Bl + nb + c2 * 8);
        }
        const unsigned short* Ac = Al + cur * 4096;
        const unsigned short* Bc = Bl + cur * 4096;

        half8 aF[4], bF[4];
        #pragma unroll
        for (int i = 0; i < 4; ++i)
            aF[i] = *(const half8*)(Ac + (wm + 16 * i + l) * 32 + 8 * q);
        #pragma unroll
        for (int j = 0; j < 4; ++j)
            bF[j] = *(const half8*)(Bc + (wn + 16 * j + l) * 32 + 8 * q);
        #pragma unroll
        for (int i = 0; i < 4; ++i)
            #pragma unroll
            for (int j = 0; j < 4; ++j)
                acc[i][j] = __builtin_amdgcn_mfma_f32_16x16x32_f16(
                    aF[i], bF[j], acc[i][j], 0, 0, 0);
        cur ^= 1;
    }
}

// ---------------------------------------------------------------------------
// Merged Q + KV projection GEMM, 1-D grid 768, XCD-affine mapping (r8).
// V output written TRANSPOSED directly into Vt[bh][d][z].
// ---------------------------------------------------------------------------
__global__ __launch_bounds__(256) void gemm_qkv(
    const unsigned short* __restrict__ Af, const unsigned short* __restrict__ At,
    const unsigned short* __restrict__ Wqt, const unsigned short* __restrict__ Wkvt,
    const float* __restrict__ bq, const float* __restrict__ bkv,
    unsigned short* __restrict__ Qo, unsigned short* __restrict__ Ko,
    unsigned short* __restrict__ Vt)
{
    __shared__ unsigned short Al[2 * 128 * 32];
    __shared__ unsigned short Bl[2 * 128 * 32];

    const int tid  = threadIdx.x;
    const int w    = tid >> 6;
    const int lane = tid & 63;
    const int q    = lane >> 4, l = lane & 15;
    const int wm = (w >> 1) * 64, wn = (w & 1) * 64;

    const int bid = blockIdx.x;
    const int xcd = bid & 7;
    const int idx = bid >> 3;                 // 0..95
    const int bx  = idx >> 2;                 // 0..23 (n-tile)
    const int by  = (idx & 3) + (xcd << 2);   // 0..31 (m-tile)
    const int m0  = by * 128;

    bool isQ = bx < 8;
    const unsigned short* A  = isQ ? Af : At;
    const unsigned short* Wt = isQ ? Wqt : Wkvt;
    const float* bias        = isQ ? bq : bkv;
    const int n0 = (isQ ? bx : (bx - 8)) * 128;

    floatx4 acc[4][4];
    #pragma unroll
    for (int i = 0; i < 4; ++i)
        #pragma unroll
        for (int j = 0; j < 4; ++j)
            acc[i][j] = (floatx4){0.f, 0.f, 0.f, 0.f};

    gemm_core(A, Wt, m0, n0, FDIM, acc, Al, Bl);

    float bj[4];
    #pragma unroll
    for (int j = 0; j < 4; ++j) bj[j] = bias[n0 + wn + 16 * j + l];

    #pragma unroll
    for (int i = 0; i < 4; ++i)
        #pragma unroll
        for (int j = 0; j < 4; ++j) {
            int n = n0 + wn + 16 * j + l;
            float vv[4];
            #pragma unroll
            for (int r = 0; r < 4; ++r) vv[r] = acc[i][j][r] + bj[j];
            int mm = m0 + wm + 16 * i + 4 * q;     // s of r=0 (4-aligned run)
            int b = mm >> 11, s0 = mm & (SEQ - 1);
            if (isQ) {
                int h = n >> 6, dd = n & 63;
                unsigned short* qp = Qo + ((size_t)(b * NH + h) * SEQ + s0) * HD + dd;
                #pragma unroll
                for (int r = 0; r < 4; ++r) qp[r * HD] = f16_1(vv[r]);
            } else if (n < FDIM) {                 // K (block-uniform branch)
                int h = n >> 6, dd = n & 63;
                unsigned short* kp = Ko + ((size_t)(b * NH + h) * SEQ + s0) * HD + dd;
                #pragma unroll
                for (int r = 0; r < 4; ++r) kp[r * HD] = f16_1(vv[r]);
            } else {                               // V -> transposed layout
                int np = n - FDIM;
                int h = np >> 6, dd = np & 63;
                uint2 o = make_uint2(pk_f16(vv[0], vv[1]), pk_f16(vv[2], vv[3]));
                *(uint2*)(Vt + ((size_t)(b * NH + h) * HD + dd) * SEQ + s0) = o;
            }
        }
}

// ---------------------------------------------------------------------------
// Out-projection GEMM: fp32 output [M][N]. 1-D grid 256, XCD-affine mapping.
// ---------------------------------------------------------------------------
__global__ __launch_bounds__(256) void gemm_out(
    const unsigned short* __restrict__ A, const unsigned short* __restrict__ Wt,
    const float* __restrict__ bias, float* __restrict__ C)
{
    __shared__ unsigned short Al[2 * 128 * 32];
    __shared__ unsigned short Bl[2 * 128 * 32];

    const int tid  = threadIdx.x;
    const int w    = tid >> 6;
    const int lane = tid & 63;
    const int q    = lane >> 4, l = lane & 15;
    const int wm = (w >> 1) * 64, wn = (w & 1) * 64;

    const int bid = blockIdx.x;
    const int xcd = bid & 7;
    const int idx = bid >> 3;                 // 0..31
    const int bx  = idx >> 2;                 // 0..7 (n-tile)
    const int by  = (idx & 3) + (xcd << 2);   // 0..31 (m-tile)
    const int m0 = by * 128, n0 = bx * 128;

    floatx4 acc[4][4];
    #pragma unroll
    for (int i = 0; i < 4; ++i)
        #pragma unroll
        for (int j = 0; j < 4; ++j)
            acc[i][j] = (floatx4){0.f, 0.f, 0.f, 0.f};

    gemm_core(A, Wt, m0, n0, FDIM, acc, Al, Bl);

    float bj[4];
    #pragma unroll
    for (int j = 0; j < 4; ++j) bj[j] = bias[n0 + wn + 16 * j + l];

    #pragma unroll
    for (int i = 0; i < 4; ++i)
        #pragma unroll
        for (int j = 0; j < 4; ++j) {
            int n = n0 + wn + 16 * j + l;
            #pragma unroll
            for (int r = 0; r < 4; ++r) {
                int m = m0 + wm + 16 * i + 4 * q + r;
                C[(size_t)m * FDIM + n] = acc[i][j][r] + bj[j];
            }
        }
}

// ---------------------------------------------------------------------------
// Row s=0 of each (b,h): reference's fully-masked row -> uniform softmax over
// all 2048 columns -> O[b,0,h*64+d] = mean_z V[bh][z][d]. Writes Og row 0
// (merge_kernel skips s==0).
// ---------------------------------------------------------------------------
__global__ __launch_bounds__(256) void row0_kernel(
    const unsigned short* __restrict__ Vtg, unsigned short* __restrict__ Og)
{
    __shared__ float red[256];
    const int bh = blockIdx.x;
    const int tid = threadIdx.x;
    const int d = tid >> 2, part = tid & 3;
    const unsigned short* vp = Vtg + ((size_t)bh * HD + d) * SEQ + part * 512;
    float s = 0.f;
    #pragma unroll
    for (int i = 0; i < 64; ++i) {
        half8 v = *(const half8*)(vp + i * 8);
        #pragma unroll
        for (int j = 0; j < 8; ++j) s += (float)v[j];
    }
    red[tid] = s;
    __syncthreads();
    if (part == 0) {
        float t = red[tid] + red[tid + 1] + red[tid + 2] + red[tid + 3];
        const int b = bh >> 4, h = bh & 15;
        Og[(size_t)b * SEQ * FDIM + h * HD + d] = f16_1(t * (1.0f / 2048.0f));
    }
}

// ---------------------------------------------------------------------------
// Flash attention, swapped-operand 32x32x16 MFMA, in-register softmax (T12),
// z-SPLIT for occupancy (1024 blocks = 4 blocks/CU). Partial O + (m,l);
// merge_kernel combines.
// Block mapping: XCD affinity (same-bh blocks share bid%8) + CU balance
// (co-resident quads stage exactly 34 tiles).
// Row sums via ones-MFMA (32x32). Defer-max THR=8.
// ---------------------------------------------------------------------------
__global__ __launch_bounds__(256, 4) void attn_kernel(
    const unsigned short* __restrict__ Qg, const unsigned short* __restrict__ Kg,
    const unsigned short* __restrict__ Vtg, unsigned short* __restrict__ Op0,
    unsigned short* __restrict__ Op1, float* __restrict__ mlb)
{
    __shared__ unsigned short Kl[2][64 * LK];
    __shared__ unsigned short Vl[2][64 * LK];

    const int tid  = threadIdx.x;
    const int w    = tid >> 6;
    const int lane = tid & 63;
    const int l31  = lane & 31;
    const int hi   = lane >> 5;

    const int bid  = blockIdx.x;
    const int x    = bid & 7;               // XCD under bid%8 round-robin
    const int j2   = (bid >> 3) & 3;
    const int jj   = (bid >> 5) & 7;
    const int q2   = (bid >> 8) & 3;
    const int bh   = (j2 << 3) | x;         // same-bh blocks share an XCD
    const int st   = (q2 & 1) ? (15 - jj) : jj;
    const int half = q2 >> 1;

    const int S0  = st << 7;             // block covers s in [S0, S0+128)
    const int sw  = S0 + 32 * w;         // wave's first query row
    const int s   = sw + l31;            // this lane's query row

    const unsigned short* Qb  = Qg  + (size_t)bh * SEQ * HD;
    const unsigned short* Kb  = Kg  + (size_t)bh * SEQ * HD;
    const unsigned short* Vtb = Vtg + (size_t)bh * HD * SEQ;

    // Q as B-operand: lane holds Q[s][16*kk + 8*hi + j]
    half8 bQ[4];
    {
        const unsigned short* qp = Qb + (size_t)s * HD + 8 * hi;
        #pragma unroll
        for (int kk = 0; kk < 4; ++kk)
            bQ[kk] = *(const half8*)(qp + 16 * kk);
    }

    half8 ones;
    #pragma unroll
    for (int j = 0; j < 8; ++j) ones[j] = (_Float16)1.0f;

    float m_run = -INFINITY, l_run = 0.f;
    floatx16 oT0 = zero16(), oT1 = zero16();   // O^T accum, d in [0,32) / [32,64)

    const int ztd  = (st << 1) + (w >> 1);   // wave's diagonal z-tile
    const int ntl  = st + 1;                 // tiles in this half
    const int zb   = half ? ntl : 0;         // first z-tile of this half
    const float L2E = 1.44269504f;

    // staging addresses: thread covers K row (srow+32*it), V row (srow+32*it)
    const int srow = tid >> 3, sc8 = (tid & 7) << 3;
    half8 kreg[2], vreg[2];

    // prologue: tile zb -> buf 0
    {
        const int z0 = zb << 6;
        #pragma unroll
        for (int it = 0; it < 2; ++it) {
            kreg[it] = *(const half8*)(Kb + (size_t)(z0 + srow + 32 * it) * HD + sc8);
            vreg[it] = *(const half8*)(Vtb + (size_t)(srow + 32 * it) * SEQ + z0 + sc8);
        }
        #pragma unroll
        for (int it = 0; it < 2; ++it) {
            *(half8*)(&Kl[0][(srow + 32 * it) * LK + sc8]) = kreg[it];
            *(half8*)(&Vl[0][(srow + 32 * it) * LK + sc8]) = vreg[it];
        }
    }

    int cur = 0;
    for (int zl = 0; zl < ntl; ++zl) {
        const int zt = zb + zl;
        const bool haveNext = (zl + 1 < ntl);
        const int z0n = (zt + 1) << 6;
        __syncthreads();                 // buf[cur] writes visible

        const unsigned short* Kc = Kl[cur];
        const unsigned short* Vc = Vl[cur];

        if (zt <= ztd) {
            const int z0 = zt << 6;
            // S^T = K @ Q^T : c0 covers z' in [0,32), c1 in [32,64); col = s
            floatx16 c0 = zero16(), c1 = zero16();
            #pragma unroll
            for (int kk = 0; kk < 4; ++kk) {
                half8 aK0 = *(const half8*)(&Kc[l31 * LK + 16 * kk + 8 * hi]);
                half8 aK1 = *(const half8*)(&Kc[(32 + l31) * LK + 16 * kk + 8 * hi]);
                c0 = __builtin_amdgcn_mfma_f32_32x32x16_f16(aK0, bQ[kk], c0, 0, 0, 0);
                c1 = __builtin_amdgcn_mfma_f32_32x32x16_f16(aK1, bQ[kk], c1, 0, 0, 0);
            }

            // prefetch next tile (issued here so HBM latency hides under
            // softmax + PV below)
            if (haveNext) {
                #pragma unroll
                for (int it = 0; it < 2; ++it) {
                    kreg[it] = *(const half8*)(Kb + (size_t)(z0n + srow + 32 * it) * HD + sc8);
                    vreg[it] = *(const half8*)(Vtb + (size_t)(srow + 32 * it) * SEQ + z0n + sc8);
                }
            }

            if (zt == ztd) {             // diagonal tile: mask z >= s
                float mval = (s == 0) ? 0.0f : -1e12f;
                #pragma unroll
                for (int r = 0; r < 16; ++r) {
                    int zl2 = (r & 3) + 8 * (r >> 2) + 4 * hi;
                    if (z0 + zl2      >= s) c0[r] = mval;
                    if (z0 + 32 + zl2 >= s) c1[r] = mval;
                }
            }

            // row max: balanced tree + one permlane32_swap
            float pm[8];
            #pragma unroll
            for (int rr = 0; rr < 8; ++rr)
                pm[rr] = fmaxf(fmaxf(c0[2 * rr], c0[2 * rr + 1]),
                               fmaxf(c1[2 * rr], c1[2 * rr + 1]));
            float rm = fmaxf(fmaxf(fmaxf(pm[0], pm[1]), fmaxf(pm[2], pm[3])),
                             fmaxf(fmaxf(pm[4], pm[5]), fmaxf(pm[6], pm[7])));
            {
                unsigned t0 = __builtin_bit_cast(unsigned, rm);
                unsigned t1 = t0;
                pl32(t0, t1);
                rm = fmaxf(__builtin_bit_cast(float, t0), __builtin_bit_cast(float, t1));
            }

            // defer-max: only rescale when running max grows by > THR=8
            if (!__all(rm <= m_run + 8.f)) {
                float mn = fmaxf(m_run, rm);
                float alpha = __expf(m_run - mn);
                m_run = mn;
                l_run *= alpha;
                #pragma unroll
                for (int r = 0; r < 16; ++r) { oT0[r] *= alpha; oT1[r] *= alpha; }
            }

            // p = exp(S - m_run) -> packed f16 pairs
            const float mb = m_run * L2E;
            unsigned pk0[8], pk1[8];
            #pragma unroll
            for (int t = 0; t < 8; ++t) {
                float a0 = __builtin_amdgcn_exp2f(fmaf(c0[2 * t],     L2E, -mb));
                float a1 = __builtin_amdgcn_exp2f(fmaf(c0[2 * t + 1], L2E, -mb));
                float b0 = __builtin_amdgcn_exp2f(fmaf(c1[2 * t],     L2E, -mb));
                float b1 = __builtin_amdgcn_exp2f(fmaf(c1[2 * t + 1], L2E, -mb));
                pk0[t] = __builtin_bit_cast(unsigned, __builtin_amdgcn_cvt_pkrtz(a0, a1));
                pk1[t] = __builtin_bit_cast(unsigned, __builtin_amdgcn_cvt_pkrtz(b0, b1));
            }
            // redistribute across lane halves: pk regs become B-frags in place
            pl32(pk0[0], pk0[2]); pl32(pk0[1], pk0[3]);
            pl32(pk0[4], pk0[6]); pl32(pk0[5], pk0[7]);
            pl32(pk1[0], pk1[2]); pl32(pk1[1], pk1[3]);
            pl32(pk1[4], pk1[6]); pl32(pk1[5], pk1[7]);
            half8 bP[4];
            bP[0] = bc4(pk0[0], pk0[1], pk0[2], pk0[3]);   // z in [ 0,16)
            bP[1] = bc4(pk0[4], pk0[5], pk0[6], pk0[7]);   // z in [16,32)
            bP[2] = bc4(pk1[0], pk1[1], pk1[2], pk1[3]);   // z in [32,48)
            bP[3] = bc4(pk1[4], pk1[5], pk1[6], pk1[7]);   // z in [48,64)

            // O^T += V^T @ P^T ; row sums via ones-MFMA on the same frags
            floatx16 lsa = zero16();
            #pragma unroll
            for (int kk = 0; kk < 4; ++kk) {
                half8 aV0 = *(const half8*)(&Vc[l31 * LK + 16 * kk + 8 * hi]);
                half8 aV1 = *(const half8*)(&Vc[(32 + l31) * LK + 16 * kk + 8 * hi]);
                oT0 = __builtin_amdgcn_mfma_f32_32x32x16_f16(aV0, bP[kk], oT0, 0, 0, 0);
                oT1 = __builtin_amdgcn_mfma_f32_32x32x16_f16(aV1, bP[kk], oT1, 0, 0, 0);
                lsa = __builtin_amdgcn_mfma_f32_32x32x16_f16(ones, bP[kk], lsa, 0, 0, 0);
            }
            l_run += lsa[0];
        } else {
            // fully-masked tile for this wave: still prefetch + commit
            if (haveNext) {
                #pragma unroll
                for (int it = 0; it < 2; ++it) {
                    kreg[it] = *(const half8*)(Kb + (size_t)(z0n + srow + 32 * it) * HD + sc8);
                    vreg[it] = *(const half8*)(Vtb + (size_t)(srow + 32 * it) * SEQ + z0n + sc8);
                }
            }
        }

        if (haveNext) {
            unsigned short* Kd = Kl[cur ^ 1];
            unsigned short* Vd = Vl[cur ^ 1];
            #pragma unroll
            for (int it = 0; it < 2; ++it) {
                *(half8*)(&Kd[(srow + 32 * it) * LK + sc8]) = kreg[it];
                *(half8*)(&Vd[(srow + 32 * it) * LK + sc8]) = vreg[it];
            }
        }
        cur ^= 1;
    }

    // epilogue: partial O (pre-normalized, f16) + (m, l) f32 for merge.
    // l_run==0 (fully-masked half) -> store zeros; m_run=-inf -> weight 0.
    float inv = (l_run > 0.f) ? (1.0f / l_run) : 0.f;
    unsigned short* Oph = half ? Op1 : Op0;
    unsigned short* op = Oph + ((size_t)bh * SEQ + s) * HD + 4 * hi;
    #pragma unroll
    for (int gg = 0; gg < 4; ++gg) {
        uint2 o0 = make_uint2(pk_f16(oT0[4 * gg + 0] * inv, oT0[4 * gg + 1] * inv),
                              pk_f16(oT0[4 * gg + 2] * inv, oT0[4 * gg + 3] * inv));
        *(uint2*)(op + 8 * gg) = o0;
        uint2 o1 = make_uint2(pk_f16(oT1[4 * gg + 0] * inv, oT1[4 * gg + 1] * inv),
                              pk_f16(oT1[4 * gg + 2] * inv, oT1[4 * gg + 3] * inv));
        *(uint2*)(op + 32 + 8 * gg) = o1;
    }
    if (hi == 0) {
        float* mlp = mlb + (((size_t)half * BH + bh) * SEQ + s) * 2;
        mlp[0] = m_run; mlp[1] = l_run;
    }
}

// ---------------------------------------------------------------------------
// Merge the two z-half partials:
// O = (e^{m1-m} l1 O1n + e^{m2-m} l2 O2n) / (e^{m1-m} l1 + e^{m2-m} l2).
// Skips s==0 (row0_kernel owns it). 4 threads/row, 16 d-elems each.
// ---------------------------------------------------------------------------
__global__ __launch_bounds__(256) void merge_kernel(
    const unsigned short* __restrict__ Op0, const unsigned short* __restrict__ Op1,
    const float* __restrict__ mlb, unsigned short* __restrict__ Og)
{
    const int tid  = threadIdx.x;
    const int blk  = blockIdx.x;            // 32 bh x 32 bands
    const int bh   = blk >> 5, band = blk & 31;
    const int r    = tid >> 2, dseg = (tid & 3) << 4;
    const int s    = (band << 6) | r;
    if (s == 0) return;                     // row0_kernel handles s==0

    const size_t row = (size_t)bh * SEQ + s;
    const float* mp0 = mlb + row * 2;
    const float* mp1 = mlb + ((size_t)BH * SEQ + row) * 2;
    float m1 = mp0[0], l1 = mp0[1];
    float m2 = mp1[0], l2 = mp1[1];
    float m  = fmaxf(m1, m2);
    float w1 = __expf(m1 - m) * l1;
    float w2 = __expf(m2 - m) * l2;
    float inv = 1.0f / (w1 + w2);           // l1 > 0 for all s >= 1
    w1 *= inv; w2 *= inv;

    const unsigned short* pa = Op0 + row * HD + dseg;
    const unsigned short* pc = Op1 + row * HD + dseg;
    half8 a0 = *(const half8*)(pa), a1 = *(const half8*)(pa + 8);
    half8 c0 = *(const half8*)(pc), c1 = *(const half8*)(pc + 8);

    float f[16];
    #pragma unroll
    for (int i = 0; i < 8; ++i) {
        f[i]     = w1 * (float)a0[i] + w2 * (float)c0[i];
        f[8 + i] = w1 * (float)a1[i] + w2 * (float)c1[i];
    }
    const int b = bh >> 4, h = bh & 15;
    unsigned short* og = Og + ((size_t)b * SEQ + s) * FDIM + h * HD + dseg;
    uint4 u0, u1;
    u0.x = pk_f16(f[0],  f[1]);  u0.y = pk_f16(f[2],  f[3]);
    u0.z = pk_f16(f[4],  f[5]);  u0.w = pk_f16(f[6],  f[7]);
    u1.x = pk_f16(f[8],  f[9]);  u1.y = pk_f16(f[10], f[11]);
    u1.z = pk_f16(f[12], f[13]); u1.w = pk_f16(f[14], f[15]);
    *(uint4*)og = u0;
    *(uint4*)(og + 8) = u1;
}

// ---------------------------------------------------------------------------
extern "C" void kernel_launch(void* const* d_in, const int* in_sizes, int n_in,
                              void* d_out, int out_size, void* d_ws, size_t ws_size,
                              hipStream_t stream) {
    const float* attend_from = (const float*)d_in[0];
    const float* attend_to   = (const float*)d_in[1];
    const float* w_q   = (const float*)d_in[2];
    const float* b_q   = (const float*)d_in[3];
    const float* w_kv  = (const float*)d_in[4];
    const float* b_kv  = (const float*)d_in[5];
    const float* w_out = (const float*)d_in[6];
    const float* b_out = (const float*)d_in[7];
    float* out = (float*)d_out;

    unsigned short* ws = (unsigned short*)d_ws;
    const size_t E = (size_t)(SB * SEQ) * FDIM;   // 4M elems
    unsigned short* Af   = ws;                    // reused: attn partial O half0
    unsigned short* At   = ws + E;                //         attn partial O half1
    unsigned short* Qb   = ws + 2 * E;
    unsigned short* Kb   = ws + 3 * E;
    unsigned short* Ob   = ws + 4 * E;            // attn output (A of out-GEMM)
    unsigned short* Vt   = ws + 5 * E;            // V written transposed by gemm_qkv
    unsigned short* Wqt  = ws + 6 * E;
    unsigned short* Wkvt = ws + 6 * E + E / 4;
    unsigned short* Wot  = ws + 6 * E + E / 4 + E / 2;
    float* mlb = (float*)Wkvt;                    // reused after gemm_qkv; 1.05 MB

    dim3 blk(256);

    cvt_all<<<dim3(5120), blk, 0, stream>>>(
        attend_from, attend_to, Af, At, w_q, w_kv, w_out, Wqt, Wkvt, Wot);
    gemm_qkv<<<dim3(768), blk, 0, stream>>>(
        Af, At, Wqt, Wkvt, b_q, b_kv, Qb, Kb, Vt);
    row0_kernel<<<dim3(BH), blk, 0, stream>>>(Vt, Ob);
    attn_kernel<<<dim3(BH * (SEQ / 128) * 2), blk, 0, stream>>>(
        Qb, Kb, Vt, Af, At, mlb);
    merge_kernel<<<dim3(BH * (SEQ / 64)), blk, 0, stream>>>(Af, At, mlb, Ob);
    gemm_out<<<dim3(256), blk, 0, stream>>>(Ob, Wot, b_out, out);
}

// Round 10
// 202.414 us; speedup vs baseline: 1.0823x; 1.0036x over previous
//
#include <hip/hip_runtime.h>
#include <math.h>

#define SB   2
#define SEQ  2048
#define FDIM 1024
#define NH   16
#define HD   64
#define BH   (SB * NH)   // 32
#define LK   72          // attention LDS row stride in f16 elems (64 + 8 pad)

typedef _Float16 half8 __attribute__((ext_vector_type(8)));
typedef __attribute__((ext_vector_type(4))) float floatx4;
typedef __attribute__((ext_vector_type(16))) float floatx16;
typedef unsigned int uintx4 __attribute__((ext_vector_type(4)));
typedef unsigned int uint2v __attribute__((ext_vector_type(2)));

__device__ __forceinline__ unsigned pk_f16(float a, float b) {
    unsigned short ha = __builtin_bit_cast(unsigned short, (_Float16)a);
    unsigned short hb = __builtin_bit_cast(unsigned short, (_Float16)b);
    return (unsigned)ha | ((unsigned)hb << 16);
}
__device__ __forceinline__ unsigned short f16_1(float a) {
    _Float16 h = (_Float16)a;
    return __builtin_bit_cast(unsigned short, h);
}
__device__ __forceinline__ void load16_lds(const unsigned short* g, unsigned short* l) {
    __builtin_amdgcn_global_load_lds(
        (const __attribute__((address_space(1))) unsigned int*)g,
        (__attribute__((address_space(3))) unsigned int*)l, 16, 0, 0);
}
// hazard-safe permlane32_swap via builtin: swaps a.hi32lanes <-> b.lo32lanes
__device__ __forceinline__ void pl32(unsigned &a, unsigned &b) {
    uint2v r = __builtin_amdgcn_permlane32_swap(a, b, false, false);
    a = r[0]; b = r[1];
}
__device__ __forceinline__ half8 bc4(unsigned a, unsigned b, unsigned c, unsigned d) {
    uintx4 t; t[0] = a; t[1] = b; t[2] = c; t[3] = d;
    return __builtin_bit_cast(half8, t);
}
__device__ __forceinline__ floatx16 zero16() {
    floatx16 z;
    #pragma unroll
    for (int i = 0; i < 16; ++i) z[i] = 0.f;
    return z;
}

// ---------------------------------------------------------------------------
// Combined precompute: blocks [0,4096) convert activations fp32->f16;
// blocks [4096,5120) transpose+convert the three weight matrices.
// ---------------------------------------------------------------------------
__global__ __launch_bounds__(256) void cvt_all(
    const float* __restrict__ in0, const float* __restrict__ in1,
    unsigned short* __restrict__ out0, unsigned short* __restrict__ out1,
    const float* __restrict__ Wq, const float* __restrict__ Wkv,
    const float* __restrict__ Wo, unsigned short* __restrict__ Wqt,
    unsigned short* __restrict__ Wkvt, unsigned short* __restrict__ Wot)
{
    __shared__ float T[64 * 65];
    const int tid = threadIdx.x;
    int bid = blockIdx.x;

    if (bid < 4096) {               // activation convert path (no LDS use)
        const float* in = (bid < 2048) ? in0 : in1;
        unsigned short* out = (bid < 2048) ? out0 : out1;
        int i = ((bid & 2047) * 256 + tid) * 8;
        float4 a = *(const float4*)(in + i);
        float4 b = *(const float4*)(in + i + 4);
        uint4 o;
        o.x = pk_f16(a.x, a.y); o.y = pk_f16(a.z, a.w);
        o.z = pk_f16(b.x, b.y); o.w = pk_f16(b.z, b.w);
        *(uint4*)(out + i) = o;
        return;
    }

    int id = bid - 4096;            // weight transpose path
    const float* W; unsigned short* Wt; int N, n0, k0;
    if (id < 256)      { W = Wq;  Wt = Wqt;  N = 1024; n0 = (id & 15) << 6; k0 = (id >> 4) << 6; }
    else if (id < 768) { id -= 256; W = Wkv; Wt = Wkvt; N = 2048; n0 = (id & 31) << 6; k0 = (id >> 5) << 6; }
    else               { id -= 768; W = Wo;  Wt = Wot;  N = 1024; n0 = (id & 15) << 6; k0 = (id >> 4) << 6; }

    #pragma unroll
    for (int i = 0; i < 4; ++i) {
        int idx = tid + (i << 8);
        int row = idx >> 4, c4 = idx & 15;
        float4 v = *(const float4*)(W + (size_t)(k0 + row) * N + n0 + (c4 << 2));
        float* tp = &T[row * 65 + (c4 << 2)];
        tp[0] = v.x; tp[1] = v.y; tp[2] = v.z; tp[3] = v.w;
    }
    __syncthreads();
    #pragma unroll
    for (int i = 0; i < 4; ++i) {
        int idx = tid + (i << 8);
        int n = idx >> 4, c4 = idx & 15;
        float x = T[(c4 * 4 + 0) * 65 + n];
        float y = T[(c4 * 4 + 1) * 65 + n];
        float z = T[(c4 * 4 + 2) * 65 + n];
        float w = T[(c4 * 4 + 3) * 65 + n];
        uint2 o = make_uint2(pk_f16(x, y), pk_f16(z, w));
        *(uint2*)(Wt + (size_t)(n0 + n) * FDIM + k0 + (c4 << 2)) = o;
    }
}

// ---------------------------------------------------------------------------
// f16 MFMA GEMM core, 128x128 tile, BK=32, double-buffered LDS.
// BANK-CONFLICT FIX (both-sides granule swizzle, rule 21): the [128][32]
// f16 tile's frag reads at fixed 16B-granule q hit only 2 of 8 bank-span
// positions per 16-lane group (8-way conflict; 3.1M conflict cycles in r9).
// Storing global granule (j ^ ((row>>1)&3)) in linear LDS slot j, and
// reading slot (q ^ ((row>>1)&3)), spreads 16 consecutive rows over all 8
// span positions exactly twice -> 2-way = free. LDS dest stays linear
// (global_load_lds requirement); only global SOURCE + read addr swizzle.
// ---------------------------------------------------------------------------
__device__ __forceinline__ void gemm_core(
    const unsigned short* __restrict__ A, const unsigned short* __restrict__ Wt,
    int m0, int n0, int K, floatx4 (&acc)[4][4],
    unsigned short* Al, unsigned short* Bl)
{
    const int tid  = threadIdx.x;
    const int w    = tid >> 6;
    const int lane = tid & 63;
    const int q    = lane >> 4, l = lane & 15;
    const int wm = (w >> 1) * 64, wn = (w & 1) * 64;

    const int c   = (w * 2) * 64 + lane;      // this thread's chunk (it=0)
    const int c2  = c + 64;                   // it=1
    const int r0 = c >> 2,  o0 = ((c & 3) ^ ((r0 >> 1) & 3)) * 8;  // src swz
    const int r1 = c2 >> 2, o1 = ((c2 & 3) ^ ((r1 >> 1) & 3)) * 8;

    // prologue: tile 0 -> buf 0
    load16_lds(A  + (size_t)(m0 + r0) * K + o0, Al + c * 8);
    load16_lds(Wt + (size_t)(n0 + r0) * K + o0, Bl + c * 8);
    load16_lds(A  + (size_t)(m0 + r1) * K + o1, Al + c2 * 8);
    load16_lds(Wt + (size_t)(n0 + r1) * K + o1, Bl + c2 * 8);

    int cur = 0;
    for (int k0 = 0; k0 < K; k0 += 32) {
        __syncthreads();                      // buf[cur] loaded & visible
        if (k0 + 32 < K) {                    // issue next tile -> buf[cur^1]
            int nb = (cur ^ 1) * 4096;
            load16_lds(A  + (size_t)(m0 + r0) * K + k0 + 32 + o0, Al + nb + c * 8);
            load16_lds(Wt + (size_t)(n0 + r0) * K + k0 + 32 + o0, Bl + nb + c * 8);
            load16_lds(A  + (size_t)(m0 + r1) * K + k0 + 32 + o1, Al + nb + c2 * 8);
            load16_lds(Wt + (size_t)(n0 + r1) * K + k0 + 32 + o1, Bl + nb + c2 * 8);
        }
        const unsigned short* Ac = Al + cur * 4096;
        const unsigned short* Bc = Bl + cur * 4096;

        half8 aF[4], bF[4];
        #pragma unroll
        for (int i = 0; i < 4; ++i) {
            int row = wm + 16 * i + l;
            int g   = q ^ ((row >> 1) & 3);   // read-side swizzle
            aF[i] = *(const half8*)(Ac + row * 32 + g * 8);
        }
        #pragma unroll
        for (int j = 0; j < 4; ++j) {
            int row = wn + 16 * j + l;
            int g   = q ^ ((row >> 1) & 3);
            bF[j] = *(const half8*)(Bc + row * 32 + g * 8);
        }
        #pragma unroll
        for (int i = 0; i < 4; ++i)
            #pragma unroll
            for (int j = 0; j < 4; ++j)
                acc[i][j] = __builtin_amdgcn_mfma_f32_16x16x32_f16(
                    aF[i], bF[j], acc[i][j], 0, 0, 0);
        cur ^= 1;
    }
}

// ---------------------------------------------------------------------------
// Merged Q + KV projection GEMM, 1-D grid 768, XCD-affine mapping (r8).
// V output written TRANSPOSED directly into Vt[bh][d][z].
// ---------------------------------------------------------------------------
__global__ __launch_bounds__(256) void gemm_qkv(
    const unsigned short* __restrict__ Af, const unsigned short* __restrict__ At,
    const unsigned short* __restrict__ Wqt, const unsigned short* __restrict__ Wkvt,
    const float* __restrict__ bq, const float* __restrict__ bkv,
    unsigned short* __restrict__ Qo, unsigned short* __restrict__ Ko,
    unsigned short* __restrict__ Vt)
{
    __shared__ unsigned short Al[2 * 128 * 32];
    __shared__ unsigned short Bl[2 * 128 * 32];

    const int tid  = threadIdx.x;
    const int w    = tid >> 6;
    const int lane = tid & 63;
    const int q    = lane >> 4, l = lane & 15;
    const int wm = (w >> 1) * 64, wn = (w & 1) * 64;

    const int bid = blockIdx.x;
    const int xcd = bid & 7;
    const int idx = bid >> 3;                 // 0..95
    const int bx  = idx >> 2;                 // 0..23 (n-tile)
    const int by  = (idx & 3) + (xcd << 2);   // 0..31 (m-tile)
    const int m0  = by * 128;

    bool isQ = bx < 8;
    const unsigned short* A  = isQ ? Af : At;
    const unsigned short* Wt = isQ ? Wqt : Wkvt;
    const float* bias        = isQ ? bq : bkv;
    const int n0 = (isQ ? bx : (bx - 8)) * 128;

    floatx4 acc[4][4];
    #pragma unroll
    for (int i = 0; i < 4; ++i)
        #pragma unroll
        for (int j = 0; j < 4; ++j)
            acc[i][j] = (floatx4){0.f, 0.f, 0.f, 0.f};

    gemm_core(A, Wt, m0, n0, FDIM, acc, Al, Bl);

    float bj[4];
    #pragma unroll
    for (int j = 0; j < 4; ++j) bj[j] = bias[n0 + wn + 16 * j + l];

    #pragma unroll
    for (int i = 0; i < 4; ++i)
        #pragma unroll
        for (int j = 0; j < 4; ++j) {
            int n = n0 + wn + 16 * j + l;
            float vv[4];
            #pragma unroll
            for (int r = 0; r < 4; ++r) vv[r] = acc[i][j][r] + bj[j];
            int mm = m0 + wm + 16 * i + 4 * q;     // s of r=0 (4-aligned run)
            int b = mm >> 11, s0 = mm & (SEQ - 1);
            if (isQ) {
                int h = n >> 6, dd = n & 63;
                unsigned short* qp = Qo + ((size_t)(b * NH + h) * SEQ + s0) * HD + dd;
                #pragma unroll
                for (int r = 0; r < 4; ++r) qp[r * HD] = f16_1(vv[r]);
            } else if (n < FDIM) {                 // K (block-uniform branch)
                int h = n >> 6, dd = n & 63;
                unsigned short* kp = Ko + ((size_t)(b * NH + h) * SEQ + s0) * HD + dd;
                #pragma unroll
                for (int r = 0; r < 4; ++r) kp[r * HD] = f16_1(vv[r]);
            } else {                               // V -> transposed layout
                int np = n - FDIM;
                int h = np >> 6, dd = np & 63;
                uint2 o = make_uint2(pk_f16(vv[0], vv[1]), pk_f16(vv[2], vv[3]));
                *(uint2*)(Vt + ((size_t)(b * NH + h) * HD + dd) * SEQ + s0) = o;
            }
        }
}

// ---------------------------------------------------------------------------
// Out-projection GEMM: fp32 output [M][N]. 1-D grid 256, XCD-affine mapping.
// ---------------------------------------------------------------------------
__global__ __launch_bounds__(256) void gemm_out(
    const unsigned short* __restrict__ A, const unsigned short* __restrict__ Wt,
    const float* __restrict__ bias, float* __restrict__ C)
{
    __shared__ unsigned short Al[2 * 128 * 32];
    __shared__ unsigned short Bl[2 * 128 * 32];

    const int tid  = threadIdx.x;
    const int w    = tid >> 6;
    const int lane = tid & 63;
    const int q    = lane >> 4, l = lane & 15;
    const int wm = (w >> 1) * 64, wn = (w & 1) * 64;

    const int bid = blockIdx.x;
    const int xcd = bid & 7;
    const int idx = bid >> 3;                 // 0..31
    const int bx  = idx >> 2;                 // 0..7 (n-tile)
    const int by  = (idx & 3) + (xcd << 2);   // 0..31 (m-tile)
    const int m0 = by * 128, n0 = bx * 128;

    floatx4 acc[4][4];
    #pragma unroll
    for (int i = 0; i < 4; ++i)
        #pragma unroll
        for (int j = 0; j < 4; ++j)
            acc[i][j] = (floatx4){0.f, 0.f, 0.f, 0.f};

    gemm_core(A, Wt, m0, n0, FDIM, acc, Al, Bl);

    float bj[4];
    #pragma unroll
    for (int j = 0; j < 4; ++j) bj[j] = bias[n0 + wn + 16 * j + l];

    #pragma unroll
    for (int i = 0; i < 4; ++i)
        #pragma unroll
        for (int j = 0; j < 4; ++j) {
            int n = n0 + wn + 16 * j + l;
            #pragma unroll
            for (int r = 0; r < 4; ++r) {
                int m = m0 + wm + 16 * i + 4 * q + r;
                C[(size_t)m * FDIM + n] = acc[i][j][r] + bj[j];
            }
        }
}

// ---------------------------------------------------------------------------
// Flash attention, swapped-operand 32x32x16 MFMA, in-register softmax (T12),
// z-SPLIT for occupancy (1024 blocks = 4 blocks/CU). Partial O + (m,l);
// merge_kernel combines.
// Block mapping: XCD affinity (same-bh blocks share bid%8) + CU balance
// (co-resident quads stage exactly 34 tiles).
// Row sums via ones-MFMA (32x32). Defer-max THR=8.
// T5: s_setprio(1) around MFMA clusters — blocks on a CU are independent
// (different z-tiles/bands), the regime where m191 measured +4-7%.
// ---------------------------------------------------------------------------
__global__ __launch_bounds__(256, 4) void attn_kernel(
    const unsigned short* __restrict__ Qg, const unsigned short* __restrict__ Kg,
    const unsigned short* __restrict__ Vtg, unsigned short* __restrict__ Op0,
    unsigned short* __restrict__ Op1, float* __restrict__ mlb)
{
    __shared__ unsigned short Kl[2][64 * LK];
    __shared__ unsigned short Vl[2][64 * LK];

    const int tid  = threadIdx.x;
    const int w    = tid >> 6;
    const int lane = tid & 63;
    const int l31  = lane & 31;
    const int hi   = lane >> 5;

    const int bid  = blockIdx.x;
    const int x    = bid & 7;               // XCD under bid%8 round-robin
    const int j2   = (bid >> 3) & 3;
    const int jj   = (bid >> 5) & 7;
    const int q2   = (bid >> 8) & 3;
    const int bh   = (j2 << 3) | x;         // same-bh blocks share an XCD
    const int st   = (q2 & 1) ? (15 - jj) : jj;
    const int half = q2 >> 1;

    const int S0  = st << 7;             // block covers s in [S0, S0+128)
    const int sw  = S0 + 32 * w;         // wave's first query row
    const int s   = sw + l31;            // this lane's query row

    const unsigned short* Qb  = Qg  + (size_t)bh * SEQ * HD;
    const unsigned short* Kb  = Kg  + (size_t)bh * SEQ * HD;
    const unsigned short* Vtb = Vtg + (size_t)bh * HD * SEQ;

    // Q as B-operand: lane holds Q[s][16*kk + 8*hi + j]
    half8 bQ[4];
    {
        const unsigned short* qp = Qb + (size_t)s * HD + 8 * hi;
        #pragma unroll
        for (int kk = 0; kk < 4; ++kk)
            bQ[kk] = *(const half8*)(qp + 16 * kk);
    }

    half8 ones;
    #pragma unroll
    for (int j = 0; j < 8; ++j) ones[j] = (_Float16)1.0f;

    float m_run = -INFINITY, l_run = 0.f;
    floatx16 oT0 = zero16(), oT1 = zero16();   // O^T accum, d in [0,32) / [32,64)

    const int ztd  = (st << 1) + (w >> 1);   // wave's diagonal z-tile
    const int ntl  = st + 1;                 // tiles in this half
    const int zb   = half ? ntl : 0;         // first z-tile of this half
    const float L2E = 1.44269504f;

    // staging addresses: thread covers K row (srow+32*it), V row (srow+32*it)
    const int srow = tid >> 3, sc8 = (tid & 7) << 3;
    half8 kreg[2], vreg[2];

    // prologue: tile zb -> buf 0
    {
        const int z0 = zb << 6;
        #pragma unroll
        for (int it = 0; it < 2; ++it) {
            kreg[it] = *(const half8*)(Kb + (size_t)(z0 + srow + 32 * it) * HD + sc8);
            vreg[it] = *(const half8*)(Vtb + (size_t)(srow + 32 * it) * SEQ + z0 + sc8);
        }
        #pragma unroll
        for (int it = 0; it < 2; ++it) {
            *(half8*)(&Kl[0][(srow + 32 * it) * LK + sc8]) = kreg[it];
            *(half8*)(&Vl[0][(srow + 32 * it) * LK + sc8]) = vreg[it];
        }
    }

    int cur = 0;
    for (int zl = 0; zl < ntl; ++zl) {
        const int zt = zb + zl;
        const bool haveNext = (zl + 1 < ntl);
        const int z0n = (zt + 1) << 6;
        __syncthreads();                 // buf[cur] writes visible

        const unsigned short* Kc = Kl[cur];
        const unsigned short* Vc = Vl[cur];

        if (zt <= ztd) {
            const int z0 = zt << 6;
            // S^T = K @ Q^T : c0 covers z' in [0,32), c1 in [32,64); col = s
            floatx16 c0 = zero16(), c1 = zero16();
            __builtin_amdgcn_s_setprio(1);
            #pragma unroll
            for (int kk = 0; kk < 4; ++kk) {
                half8 aK0 = *(const half8*)(&Kc[l31 * LK + 16 * kk + 8 * hi]);
                half8 aK1 = *(const half8*)(&Kc[(32 + l31) * LK + 16 * kk + 8 * hi]);
                c0 = __builtin_amdgcn_mfma_f32_32x32x16_f16(aK0, bQ[kk], c0, 0, 0, 0);
                c1 = __builtin_amdgcn_mfma_f32_32x32x16_f16(aK1, bQ[kk], c1, 0, 0, 0);
            }
            __builtin_amdgcn_s_setprio(0);

            // prefetch next tile (issued here so HBM latency hides under
            // softmax + PV below)
            if (haveNext) {
                #pragma unroll
                for (int it = 0; it < 2; ++it) {
                    kreg[it] = *(const half8*)(Kb + (size_t)(z0n + srow + 32 * it) * HD + sc8);
                    vreg[it] = *(const half8*)(Vtb + (size_t)(srow + 32 * it) * SEQ + z0n + sc8);
                }
            }

            if (zt == ztd) {             // diagonal tile: mask z >= s
                float mval = (s == 0) ? 0.0f : -1e12f;
                #pragma unroll
                for (int r = 0; r < 16; ++r) {
                    int zl2 = (r & 3) + 8 * (r >> 2) + 4 * hi;
                    if (z0 + zl2      >= s) c0[r] = mval;
                    if (z0 + 32 + zl2 >= s) c1[r] = mval;
                }
            }

            // row max: balanced tree + one permlane32_swap
            float pm[8];
            #pragma unroll
            for (int rr = 0; rr < 8; ++rr)
                pm[rr] = fmaxf(fmaxf(c0[2 * rr], c0[2 * rr + 1]),
                               fmaxf(c1[2 * rr], c1[2 * rr + 1]));
            float rm = fmaxf(fmaxf(fmaxf(pm[0], pm[1]), fmaxf(pm[2], pm[3])),
                             fmaxf(fmaxf(pm[4], pm[5]), fmaxf(pm[6], pm[7])));
            {
                unsigned t0 = __builtin_bit_cast(unsigned, rm);
                unsigned t1 = t0;
                pl32(t0, t1);
                rm = fmaxf(__builtin_bit_cast(float, t0), __builtin_bit_cast(float, t1));
            }

            // defer-max: only rescale when running max grows by > THR=8
            if (!__all(rm <= m_run + 8.f)) {
                float mn = fmaxf(m_run, rm);
                float alpha = __expf(m_run - mn);
                m_run = mn;
                l_run *= alpha;
                #pragma unroll
                for (int r = 0; r < 16; ++r) { oT0[r] *= alpha; oT1[r] *= alpha; }
            }

            // p = exp(S - m_run) -> packed f16 pairs
            const float mb = m_run * L2E;
            unsigned pk0[8], pk1[8];
            #pragma unroll
            for (int t = 0; t < 8; ++t) {
                float a0 = __builtin_amdgcn_exp2f(fmaf(c0[2 * t],     L2E, -mb));
                float a1 = __builtin_amdgcn_exp2f(fmaf(c0[2 * t + 1], L2E, -mb));
                float b0 = __builtin_amdgcn_exp2f(fmaf(c1[2 * t],     L2E, -mb));
                float b1 = __builtin_amdgcn_exp2f(fmaf(c1[2 * t + 1], L2E, -mb));
                pk0[t] = __builtin_bit_cast(unsigned, __builtin_amdgcn_cvt_pkrtz(a0, a1));
                pk1[t] = __builtin_bit_cast(unsigned, __builtin_amdgcn_cvt_pkrtz(b0, b1));
            }
            // redistribute across lane halves: pk regs become B-frags in place
            pl32(pk0[0], pk0[2]); pl32(pk0[1], pk0[3]);
            pl32(pk0[4], pk0[6]); pl32(pk0[5], pk0[7]);
            pl32(pk1[0], pk1[2]); pl32(pk1[1], pk1[3]);
            pl32(pk1[4], pk1[6]); pl32(pk1[5], pk1[7]);
            half8 bP[4];
            bP[0] = bc4(pk0[0], pk0[1], pk0[2], pk0[3]);   // z in [ 0,16)
            bP[1] = bc4(pk0[4], pk0[5], pk0[6], pk0[7]);   // z in [16,32)
            bP[2] = bc4(pk1[0], pk1[1], pk1[2], pk1[3]);   // z in [32,48)
            bP[3] = bc4(pk1[4], pk1[5], pk1[6], pk1[7]);   // z in [48,64)

            // O^T += V^T @ P^T ; row sums via ones-MFMA on the same frags
            floatx16 lsa = zero16();
            __builtin_amdgcn_s_setprio(1);
            #pragma unroll
            for (int kk = 0; kk < 4; ++kk) {
                half8 aV0 = *(const half8*)(&Vc[l31 * LK + 16 * kk + 8 * hi]);
                half8 aV1 = *(const half8*)(&Vc[(32 + l31) * LK + 16 * kk + 8 * hi]);
                oT0 = __builtin_amdgcn_mfma_f32_32x32x16_f16(aV0, bP[kk], oT0, 0, 0, 0);
                oT1 = __builtin_amdgcn_mfma_f32_32x32x16_f16(aV1, bP[kk], oT1, 0, 0, 0);
                lsa = __builtin_amdgcn_mfma_f32_32x32x16_f16(ones, bP[kk], lsa, 0, 0, 0);
            }
            __builtin_amdgcn_s_setprio(0);
            l_run += lsa[0];
        } else {
            // fully-masked tile for this wave: still prefetch + commit
            if (haveNext) {
                #pragma unroll
                for (int it = 0; it < 2; ++it) {
                    kreg[it] = *(const half8*)(Kb + (size_t)(z0n + srow + 32 * it) * HD + sc8);
                    vreg[it] = *(const half8*)(Vtb + (size_t)(srow + 32 * it) * SEQ + z0n + sc8);
                }
            }
        }

        if (haveNext) {
            unsigned short* Kd = Kl[cur ^ 1];
            unsigned short* Vd = Vl[cur ^ 1];
            #pragma unroll
            for (int it = 0; it < 2; ++it) {
                *(half8*)(&Kd[(srow + 32 * it) * LK + sc8]) = kreg[it];
                *(half8*)(&Vd[(srow + 32 * it) * LK + sc8]) = vreg[it];
            }
        }
        cur ^= 1;
    }

    // epilogue: partial O (pre-normalized, f16) + (m, l) f32 for merge.
    // l_run==0 (fully-masked half) -> store zeros; m_run=-inf -> weight 0.
    float inv = (l_run > 0.f) ? (1.0f / l_run) : 0.f;
    unsigned short* Oph = half ? Op1 : Op0;
    unsigned short* op = Oph + ((size_t)bh * SEQ + s) * HD + 4 * hi;
    #pragma unroll
    for (int gg = 0; gg < 4; ++gg) {
        uint2 o0 = make_uint2(pk_f16(oT0[4 * gg + 0] * inv, oT0[4 * gg + 1] * inv),
                              pk_f16(oT0[4 * gg + 2] * inv, oT0[4 * gg + 3] * inv));
        *(uint2*)(op + 8 * gg) = o0;
        uint2 o1 = make_uint2(pk_f16(oT1[4 * gg + 0] * inv, oT1[4 * gg + 1] * inv),
                              pk_f16(oT1[4 * gg + 2] * inv, oT1[4 * gg + 3] * inv));
        *(uint2*)(op + 32 + 8 * gg) = o1;
    }
    if (hi == 0) {
        float* mlp = mlb + (((size_t)half * BH + bh) * SEQ + s) * 2;
        mlp[0] = m_run; mlp[1] = l_run;
    }
}

// ---------------------------------------------------------------------------
// Merge the two z-half partials + (folded-in) row-0 path.
// Blocks [0,1024): O = (e^{m1-m}l1 O1n + e^{m2-m}l2 O2n)/(e^{m1-m}l1+e^{m2-m}l2),
//   skipping s==0. Blocks [1024,1056): row s=0 of bh = blk-1024 — the
//   reference's fully-masked row 0 is a uniform softmax over all 2048
//   columns -> O = mean_z V (computed from Vt column sums).
// ---------------------------------------------------------------------------
__global__ __launch_bounds__(256) void merge_kernel(
    const unsigned short* __restrict__ Op0, const unsigned short* __restrict__ Op1,
    const float* __restrict__ mlb, const unsigned short* __restrict__ Vtg,
    unsigned short* __restrict__ Og)
{
    __shared__ float red[256];
    const int tid  = threadIdx.x;
    const int blk  = blockIdx.x;

    if (blk >= 1024) {                      // row-0 path
        const int bh = blk - 1024;
        const int d = tid >> 2, part = tid & 3;
        const unsigned short* vp = Vtg + ((size_t)bh * HD + d) * SEQ + part * 512;
        float sm = 0.f;
        #pragma unroll
        for (int i = 0; i < 64; ++i) {
            half8 v = *(const half8*)(vp + i * 8);
            #pragma unroll
            for (int j = 0; j < 8; ++j) sm += (float)v[j];
        }
        red[tid] = sm;
        __syncthreads();
        if (part == 0) {
            float t = red[tid] + red[tid + 1] + red[tid + 2] + red[tid + 3];
            const int b = bh >> 4, h = bh & 15;
            Og[(size_t)b * SEQ * FDIM + h * HD + d] = f16_1(t * (1.0f / 2048.0f));
        }
        return;
    }

    const int bh   = blk >> 5, band = blk & 31;
    const int r    = tid >> 2, dseg = (tid & 3) << 4;
    const int s    = (band << 6) | r;
    if (s == 0) return;                     // row-0 path handles s==0

    const size_t row = (size_t)bh * SEQ + s;
    const float* mp0 = mlb + row * 2;
    const float* mp1 = mlb + ((size_t)BH * SEQ + row) * 2;
    float m1 = mp0[0], l1 = mp0[1];
    float m2 = mp1[0], l2 = mp1[1];
    float m  = fmaxf(m1, m2);
    float w1 = __expf(m1 - m) * l1;
    float w2 = __expf(m2 - m) * l2;
    float inv = 1.0f / (w1 + w2);           // l1 > 0 for all s >= 1
    w1 *= inv; w2 *= inv;

    const unsigned short* pa = Op0 + row * HD + dseg;
    const unsigned short* pc = Op1 + row * HD + dseg;
    half8 a0 = *(const half8*)(pa), a1 = *(const half8*)(pa + 8);
    half8 c0 = *(const half8*)(pc), c1 = *(const half8*)(pc + 8);

    float f[16];
    #pragma unroll
    for (int i = 0; i < 8; ++i) {
        f[i]     = w1 * (float)a0[i] + w2 * (float)c0[i];
        f[8 + i] = w1 * (float)a1[i] + w2 * (float)c1[i];
    }
    const int b = bh >> 4, h = bh & 15;
    unsigned short* og = Og + ((size_t)b * SEQ + s) * FDIM + h * HD + dseg;
    uint4 u0, u1;
    u0.x = pk_f16(f[0],  f[1]);  u0.y = pk_f16(f[2],  f[3]);
    u0.z = pk_f16(f[4],  f[5]);  u0.w = pk_f16(f[6],  f[7]);
    u1.x = pk_f16(f[8],  f[9]);  u1.y = pk_f16(f[10], f[11]);
    u1.z = pk_f16(f[12], f[13]); u1.w = pk_f16(f[14], f[15]);
    *(uint4*)og = u0;
    *(uint4*)(og + 8) = u1;
}

// ---------------------------------------------------------------------------
extern "C" void kernel_launch(void* const* d_in, const int* in_sizes, int n_in,
                              void* d_out, int out_size, void* d_ws, size_t ws_size,
                              hipStream_t stream) {
    const float* attend_from = (const float*)d_in[0];
    const float* attend_to   = (const float*)d_in[1];
    const float* w_q   = (const float*)d_in[2];
    const float* b_q   = (const float*)d_in[3];
    const float* w_kv  = (const float*)d_in[4];
    const float* b_kv  = (const float*)d_in[5];
    const float* w_out = (const float*)d_in[6];
    const float* b_out = (const float*)d_in[7];
    float* out = (float*)d_out;

    unsigned short* ws = (unsigned short*)d_ws;
    const size_t E = (size_t)(SB * SEQ) * FDIM;   // 4M elems
    unsigned short* Af   = ws;                    // reused: attn partial O half0
    unsigned short* At   = ws + E;                //         attn partial O half1
    unsigned short* Qb   = ws + 2 * E;
    unsigned short* Kb   = ws + 3 * E;
    unsigned short* Ob   = ws + 4 * E;            // attn output (A of out-GEMM)
    unsigned short* Vt   = ws + 5 * E;            // V written transposed by gemm_qkv
    unsigned short* Wqt  = ws + 6 * E;
    unsigned short* Wkvt = ws + 6 * E + E / 4;
    unsigned short* Wot  = ws + 6 * E + E / 4 + E / 2;
    float* mlb = (float*)Wkvt;                    // reused after gemm_qkv; 1.05 MB

    dim3 blk(256);

    cvt_all<<<dim3(5120), blk, 0, stream>>>(
        attend_from, attend_to, Af, At, w_q, w_kv, w_out, Wqt, Wkvt, Wot);
    gemm_qkv<<<dim3(768), blk, 0, stream>>>(
        Af, At, Wqt, Wkvt, b_q, b_kv, Qb, Kb, Vt);
    attn_kernel<<<dim3(BH * (SEQ / 128) * 2), blk, 0, stream>>>(
        Qb, Kb, Vt, Af, At, mlb);
    merge_kernel<<<dim3(BH * (SEQ / 64) + BH), blk, 0, stream>>>(
        Af, At, mlb, Vt, Ob);
    gemm_out<<<dim3(256), blk, 0, stream>>>(Ob, Wot, b_out, out);
}